// Round 3
// baseline (184.599 us; speedup 1.0000x reference)
//
#include <hip/hip_runtime.h>
#include <hip/hip_bf16.h>
#include <cstdint>

#define GN 4096      // N nodes
#define GIN 128      // IN_F
#define GF 64        // OUT_F
#define GH 8         // heads
#define GHF (GH*GF)  // 512
#define LOG2E 1.4426950408889634f

typedef __attribute__((ext_vector_type(8))) short short8v;
typedef __attribute__((ext_vector_type(4))) float f32x4;

__device__ __forceinline__ short f2bf(float x) {           // RNE float->bf16
    uint32_t u = __float_as_uint(x);
    uint32_t r = u + 0x7fffu + ((u >> 16) & 1u);
    return (short)(r >> 16);
}
__device__ __forceinline__ float bf2f(short h) {
    return __uint_as_float(((uint32_t)(unsigned short)h) << 16);
}
__device__ __forceinline__ float leaky(float t) { return fmaxf(t, 0.2f * t); }
__device__ __forceinline__ float exp2_hw(float x) {        // single v_exp_f32
    float r;
    asm("v_exp_f32 %0, %1" : "=v"(r) : "v"(x));
    return r;
}
__device__ __forceinline__ uint32_t cvt_pk_bf16(float lo, float hi) {  // RNE pack: lo16=bf16(lo), hi16=bf16(hi)
    uint32_t r;
    asm("v_cvt_pk_bf16_f32 %0, %1, %2" : "=v"(r) : "v"(lo), "v"(hi));
    return r;
}

// ---------------- Kernel 1: projection xp = A @ Wp^T (fp32) ----------------
__global__ __launch_bounds__(256) void gat_proj(const float* __restrict__ A,
                                                const float* __restrict__ W,
                                                float* __restrict__ xp) {
    __shared__ float As[64][129];
    __shared__ float Ws[64][129];
    const int n0 = blockIdx.x * 64;
    const int j0 = blockIdx.y * 64;
    const int tid = threadIdx.x;
    const float4* A4 = (const float4*)A;
    const float4* W4 = (const float4*)W;
#pragma unroll
    for (int i = 0; i < 8; ++i) {
        int idx = tid + i * 256;
        int r = idx >> 5, c4 = idx & 31;
        float4 v = A4[(size_t)(n0 + r) * 32 + c4];
        As[r][c4 * 4 + 0] = v.x; As[r][c4 * 4 + 1] = v.y;
        As[r][c4 * 4 + 2] = v.z; As[r][c4 * 4 + 3] = v.w;
        float4 w = W4[(size_t)(j0 + r) * 32 + c4];
        Ws[r][c4 * 4 + 0] = w.x; Ws[r][c4 * 4 + 1] = w.y;
        Ws[r][c4 * 4 + 2] = w.z; Ws[r][c4 * 4 + 3] = w.w;
    }
    __syncthreads();
    const int tx = tid & 15, ty = tid >> 4;
    float acc[4][4] = {};
    for (int k = 0; k < 128; ++k) {
        float a[4], b[4];
#pragma unroll
        for (int i = 0; i < 4; ++i) { a[i] = As[ty * 4 + i][k]; b[i] = Ws[tx * 4 + i][k]; }
#pragma unroll
        for (int i = 0; i < 4; ++i)
#pragma unroll
            for (int j = 0; j < 4; ++j) acc[i][j] = fmaf(a[i], b[j], acc[i][j]);
    }
#pragma unroll
    for (int i = 0; i < 4; ++i)
#pragma unroll
        for (int j = 0; j < 4; ++j)
            xp[(size_t)(n0 + ty * 4 + i) * GHF + (j0 + tx * 4 + j)] = acc[i][j];
}

// ---------------- Kernel 2: ss/st ----------------
__global__ __launch_bounds__(256) void gat_scores(const float* __restrict__ xp,
                                                  const float* __restrict__ a_src,
                                                  const float* __restrict__ a_tgt,
                                                  float* __restrict__ ss,
                                                  float* __restrict__ st) {
    const int lane = threadIdx.x & 63;
    const int w = threadIdx.x >> 6;
    const int r = blockIdx.x * 4 + w;
    const int h = r >> 12;
    const int n = r & 4095;
    float x = xp[(size_t)n * GHF + h * GF + lane];
    float s1 = x * a_src[h * GF + lane];
    float s2 = x * a_tgt[h * GF + lane];
#pragma unroll
    for (int d = 1; d < 64; d <<= 1) {
        s1 += __shfl_xor(s1, d);
        s2 += __shfl_xor(s2, d);
    }
    if (lane == 0) {
        ss[h * GN + n] = s1;
        st[h * GN + n] = s2;
    }
}

// ---------------- Kernel 3: stmax[h] = max_n st[h][n] ----------------
__global__ __launch_bounds__(512) void gat_stmax(const float* __restrict__ st,
                                                 float* __restrict__ stmax) {
    const int h = threadIdx.x >> 6;
    const int lane = threadIdx.x & 63;
    float m = -1e30f;
    for (int i = lane; i < GN; i += 64) m = fmaxf(m, st[h * GN + i]);
#pragma unroll
    for (int d = 1; d < 64; d <<= 1) m = fmaxf(m, __shfl_xor(m, d));
    if (lane == 0) stmax[h] = m;
}

// ---------------- Kernel 4: xp -> MFMA B-fragment layout, bf16 hi/lo ----------------
__global__ __launch_bounds__(256) void gat_fragconv(const float* __restrict__ xp,
                                                    short* __restrict__ bh,
                                                    short* __restrict__ bl) {
    const int idx = blockIdx.x * 256 + threadIdx.x;   // (h,t,cf,lane)
    const int lane = idx & 63;
    const int cf = (idx >> 6) & 3;
    const int t = (idx >> 8) & 127;
    const int h = idx >> 15;
    const int g = lane >> 4, c = lane & 15;
    const int col = h * GF + cf * 16 + c;
    const int m0 = t * 32 + g * 8;
    short8v vh, vl;
#pragma unroll
    for (int j = 0; j < 8; ++j) {
        float x = xp[(size_t)(m0 + j) * GHF + col];
        short hi = f2bf(x);
        vh[j] = hi;
        vl[j] = f2bf(x - bf2f(hi));
    }
    ((short8v*)bh)[idx] = vh;
    ((short8v*)bl)[idx] = vl;
}

// ---------------- Kernel 5: flash attention, MFMA, fixed softmax bound, m-split ----------------
// Block = 512 thr = 8 waves, ALL waves same head (L1 frag sharing), adjacent q-tiles.
__global__ __launch_bounds__(512, 4) void gat_attn_mfma(const short* __restrict__ bh,
                                                        const short* __restrict__ bl,
                                                        const float* __restrict__ ss,
                                                        const float* __restrict__ st,
                                                        const float* __restrict__ stmax,
                                                        const float* __restrict__ mask,
                                                        float* __restrict__ acc_p,
                                                        float* __restrict__ l_p,
                                                        int S) {
    const int lane = threadIdx.x & 63;
    const int wid = threadIdx.x >> 6;
    const int h = blockIdx.y;
    const int q0 = blockIdx.x * 256 + wid * 32;
    const int s = blockIdx.z;
    const int TPS = 128 / S;                 // 32-key tiles per split
    const int g = lane >> 4;

    const int qa = q0 + (lane & 15);
    const int qb = qa + 16;
    const float ssa = ss[h * GN + qa];
    const float ssb = ss[h * GN + qb];
    const float smx = stmax[h];
    const float ca = leaky(ssa + smx);       // fixed softmax bound
    const float cb = leaky(ssb + smx);
    const float caL = ca * LOG2E, cbL = cb * LOG2E;

    f32x4 acc[2][4];
#pragma unroll
    for (int qf = 0; qf < 2; ++qf)
#pragma unroll
        for (int cf = 0; cf < 4; ++cf) acc[qf][cf] = (f32x4){0.f, 0.f, 0.f, 0.f};
    float lsa = 0.f, lsb = 0.f;

    const int t0 = s * TPS;
    // walking pointers (per-tile stride)
    const float4* stp = (const float4*)&st[h * GN + t0 * 32 + g * 8];
    const float4* mpa = (const float4*)&mask[(size_t)qa * GN + t0 * 32 + g * 8];
    const float4* mpb = (const float4*)&mask[(size_t)qb * GN + t0 * 32 + g * 8];
    const short8v* bhp = (const short8v*)bh + ((size_t)(h * 128 + t0) * 4) * 64 + lane;
    const short8v* blp = (const short8v*)bl + ((size_t)(h * 128 + t0) * 4) * 64 + lane;

    for (int t = 0; t < TPS; ++t) {
        float4 st0 = stp[0], st1 = stp[1];
        float4 ma0 = mpa[0], ma1 = mpa[1];
        float4 mb0 = mpb[0], mb1 = mpb[1];
        short8v Bh[4], Bl[4];
#pragma unroll
        for (int cf = 0; cf < 4; ++cf) { Bh[cf] = bhp[cf * 64]; Bl[cf] = blp[cf * 64]; }
        stp += 8; mpa += 8; mpb += 8; bhp += 256; blp += 256;

        float stv[8] = {st0.x, st0.y, st0.z, st0.w, st1.x, st1.y, st1.z, st1.w};
        float mav[8] = {ma0.x, ma0.y, ma0.z, ma0.w, ma1.x, ma1.y, ma1.z, ma1.w};
        float mbv[8] = {mb0.x, mb0.y, mb0.z, mb0.w, mb1.x, mb1.y, mb1.z, mb1.w};

        float pa[8], pb[8];
#pragma unroll
        for (int j = 0; j < 8; ++j) {
            float sa = leaky(ssa + stv[j]) + mav[j];
            pa[j] = exp2_hw(fmaf(sa, LOG2E, -caL));
            float sb = leaky(ssb + stv[j]) + mbv[j];
            pb[j] = exp2_hw(fmaf(sb, LOG2E, -cbL));
        }
#pragma unroll
        for (int j = 0; j < 8; ++j) { lsa += pa[j]; lsb += pb[j]; }

        union { uint32_t u[4]; short8v v; } Pa, Pb;
#pragma unroll
        for (int w = 0; w < 4; ++w) {
            Pa.u[w] = cvt_pk_bf16(pa[2 * w], pa[2 * w + 1]);
            Pb.u[w] = cvt_pk_bf16(pb[2 * w], pb[2 * w + 1]);
        }
#pragma unroll
        for (int cf = 0; cf < 4; ++cf) {
            acc[0][cf] = __builtin_amdgcn_mfma_f32_16x16x32_bf16(Pa.v, Bh[cf], acc[0][cf], 0, 0, 0);
            acc[0][cf] = __builtin_amdgcn_mfma_f32_16x16x32_bf16(Pa.v, Bl[cf], acc[0][cf], 0, 0, 0);
            acc[1][cf] = __builtin_amdgcn_mfma_f32_16x16x32_bf16(Pb.v, Bh[cf], acc[1][cf], 0, 0, 0);
            acc[1][cf] = __builtin_amdgcn_mfma_f32_16x16x32_bf16(Pb.v, Bl[cf], acc[1][cf], 0, 0, 0);
        }
    }

    // partial row-sums: combine the 4 k-groups (lanes l, l^16, l^32, l^48)
    lsa += __shfl_xor(lsa, 16); lsa += __shfl_xor(lsa, 32);
    lsb += __shfl_xor(lsb, 16); lsb += __shfl_xor(lsb, 32);
    if (lane < 16) {
        l_p[(size_t)(s * GH + h) * GN + qa] = lsa;
        l_p[(size_t)(s * GH + h) * GN + qb] = lsb;
    }
    // store partial acc: D layout col=lane&15, row=(lane>>4)*4+r
#pragma unroll
    for (int qf = 0; qf < 2; ++qf)
#pragma unroll
        for (int cf = 0; cf < 4; ++cf)
#pragma unroll
            for (int r = 0; r < 4; ++r) {
                int row = q0 + qf * 16 + (lane >> 4) * 4 + r;
                int col = cf * 16 + (lane & 15);
                acc_p[((size_t)(s * GH + h) * GN + row) * GF + col] = acc[qf][cf][r];
            }
}

// ---------------- Kernel 6: combine splits, head-mean, relu (float4) ----------------
__global__ __launch_bounds__(256) void gat_combine(const float* __restrict__ acc_p,
                                                   const float* __restrict__ l_p,
                                                   float* __restrict__ out, int S) {
    const int idx = blockIdx.x * 256 + threadIdx.x;    // n*16 + f4
    const int n = idx >> 4, f4 = idx & 15;
    const float4* ap = (const float4*)acc_p;
    float4 r = {0.f, 0.f, 0.f, 0.f};
#pragma unroll
    for (int h = 0; h < GH; ++h) {
        float4 a = {0.f, 0.f, 0.f, 0.f};
        float l = 0.f;
        for (int s = 0; s < S; ++s) {
            float4 v = ap[((size_t)(s * GH + h) * GN + n) * 16 + f4];
            a.x += v.x; a.y += v.y; a.z += v.z; a.w += v.w;
            l += l_p[(size_t)(s * GH + h) * GN + n];
        }
        float il = 1.0f / l;
        r.x += a.x * il; r.y += a.y * il; r.z += a.z * il; r.w += a.w * il;
    }
    float4 o;
    o.x = fmaxf(r.x * 0.125f, 0.f);
    o.y = fmaxf(r.y * 0.125f, 0.f);
    o.z = fmaxf(r.z * 0.125f, 0.f);
    o.w = fmaxf(r.w * 0.125f, 0.f);
    ((float4*)out)[idx] = o;
}

extern "C" void kernel_launch(void* const* d_in, const int* in_sizes, int n_in,
                              void* d_out, int out_size, void* d_ws, size_t ws_size,
                              hipStream_t stream) {
    const float* A     = (const float*)d_in[0];
    const float* mask  = (const float*)d_in[1];
    const float* Wp    = (const float*)d_in[2];
    const float* a_src = (const float*)d_in[3];
    const float* a_tgt = (const float*)d_in[4];
    float* out = (float*)d_out;

    char* w = (char*)d_ws;
    float* xp    = (float*)w;              w += (size_t)GN * GHF * 4;        // 8 MB
    float* ss    = (float*)w;              w += (size_t)GH * GN * 4;
    float* st    = (float*)w;              w += (size_t)GH * GN * 4;
    float* stmx  = (float*)w;              w += 256;
    short* bh    = (short*)w;              w += (size_t)GH * 128 * 4 * 64 * 8 * 2; // 4 MB
    short* bl    = (short*)w;              w += (size_t)GH * 128 * 4 * 64 * 8 * 2; // 4 MB
    size_t base = (size_t)(w - (char*)d_ws);
    size_t per_s = (size_t)GH * GN * GF * 4 + (size_t)GH * GN * 4;           // 8.5 MB
    int S = 4;
    while (S > 1 && base + (size_t)S * per_s > ws_size) S >>= 1;
    float* acc_p = (float*)w;              w += (size_t)S * GH * GN * GF * 4;
    float* l_p   = (float*)w;

    gat_proj<<<dim3(GN / 64, GHF / 64), 256, 0, stream>>>(A, Wp, xp);
    gat_scores<<<(GH * GN) / 4, 256, 0, stream>>>(xp, a_src, a_tgt, ss, st);
    gat_stmax<<<1, 512, 0, stream>>>(st, stmx);
    gat_fragconv<<<(GH * 128 * 4 * 64) / 256, 256, 0, stream>>>(xp, bh, bl);
    gat_attn_mfma<<<dim3(GN / 256, GH, S), 512, 0, stream>>>(bh, bl, ss, st, stmx, mask,
                                                             acc_p, l_p, S);
    gat_combine<<<(GN * 16) / 256, 256, 0, stream>>>(acc_p, l_p, out, S);
}

// Round 5
// 150.700 us; speedup vs baseline: 1.2249x; 1.2249x over previous
//
#include <hip/hip_runtime.h>
#include <hip/hip_bf16.h>
#include <cstdint>

#define GN 4096      // N nodes
#define GIN 128      // IN_F
#define GF 64        // OUT_F
#define GH 8         // heads
#define GHF (GH*GF)  // 512
#define LOG2E 1.4426950408889634f

typedef __attribute__((ext_vector_type(8))) short short8v;
typedef __attribute__((ext_vector_type(4))) float f32x4;

__device__ __forceinline__ short f2bf(float x) {           // RNE float->bf16
    uint32_t u = __float_as_uint(x);
    uint32_t r = u + 0x7fffu + ((u >> 16) & 1u);
    return (short)(r >> 16);
}
__device__ __forceinline__ float bf2f(short h) {
    return __uint_as_float(((uint32_t)(unsigned short)h) << 16);
}
__device__ __forceinline__ float leaky(float t) { return fmaxf(t, 0.2f * t); }
__device__ __forceinline__ float exp2_hw(float x) {        // single v_exp_f32
    float r;
    asm("v_exp_f32 %0, %1" : "=v"(r) : "v"(x));
    return r;
}
__device__ __forceinline__ uint32_t cvt_pk_bf16(float lo, float hi) {
    uint32_t r;
    asm("v_cvt_pk_bf16_f32 %0, %1, %2" : "=v"(r) : "v"(lo), "v"(hi));
    return r;
}

// ---------------- Kernel 1: projection xp = A @ Wp^T (fp32) ----------------
__global__ __launch_bounds__(256) void gat_proj(const float* __restrict__ A,
                                                const float* __restrict__ W,
                                                float* __restrict__ xp) {
    __shared__ float As[64][129];
    __shared__ float Ws[64][129];
    const int n0 = blockIdx.x * 64;
    const int j0 = blockIdx.y * 64;
    const int tid = threadIdx.x;
    const float4* A4 = (const float4*)A;
    const float4* W4 = (const float4*)W;
#pragma unroll
    for (int i = 0; i < 8; ++i) {
        int idx = tid + i * 256;
        int r = idx >> 5, c4 = idx & 31;
        float4 v = A4[(size_t)(n0 + r) * 32 + c4];
        As[r][c4 * 4 + 0] = v.x; As[r][c4 * 4 + 1] = v.y;
        As[r][c4 * 4 + 2] = v.z; As[r][c4 * 4 + 3] = v.w;
        float4 w = W4[(size_t)(j0 + r) * 32 + c4];
        Ws[r][c4 * 4 + 0] = w.x; Ws[r][c4 * 4 + 1] = w.y;
        Ws[r][c4 * 4 + 2] = w.z; Ws[r][c4 * 4 + 3] = w.w;
    }
    __syncthreads();
    const int tx = tid & 15, ty = tid >> 4;
    float acc[4][4] = {};
    for (int k = 0; k < 128; ++k) {
        float a[4], b[4];
#pragma unroll
        for (int i = 0; i < 4; ++i) { a[i] = As[ty * 4 + i][k]; b[i] = Ws[tx * 4 + i][k]; }
#pragma unroll
        for (int i = 0; i < 4; ++i)
#pragma unroll
            for (int j = 0; j < 4; ++j) acc[i][j] = fmaf(a[i], b[j], acc[i][j]);
    }
#pragma unroll
    for (int i = 0; i < 4; ++i)
#pragma unroll
        for (int j = 0; j < 4; ++j)
            xp[(size_t)(n0 + ty * 4 + i) * GHF + (j0 + tx * 4 + j)] = acc[i][j];
}

// ---------------- Kernel 2: ss/st ----------------
__global__ __launch_bounds__(256) void gat_scores(const float* __restrict__ xp,
                                                  const float* __restrict__ a_src,
                                                  const float* __restrict__ a_tgt,
                                                  float* __restrict__ ss,
                                                  float* __restrict__ st) {
    const int lane = threadIdx.x & 63;
    const int w = threadIdx.x >> 6;
    const int r = blockIdx.x * 4 + w;
    const int h = r >> 12;
    const int n = r & 4095;
    float x = xp[(size_t)n * GHF + h * GF + lane];
    float s1 = x * a_src[h * GF + lane];
    float s2 = x * a_tgt[h * GF + lane];
#pragma unroll
    for (int d = 1; d < 64; d <<= 1) {
        s1 += __shfl_xor(s1, d);
        s2 += __shfl_xor(s2, d);
    }
    if (lane == 0) {
        ss[h * GN + n] = s1;
        st[h * GN + n] = s2;
    }
}

// ---------------- Kernel 3: stmax[h] = max_n st[h][n] ----------------
__global__ __launch_bounds__(512) void gat_stmax(const float* __restrict__ st,
                                                 float* __restrict__ stmax) {
    const int h = threadIdx.x >> 6;
    const int lane = threadIdx.x & 63;
    float m = -1e30f;
    for (int i = lane; i < GN; i += 64) m = fmaxf(m, st[h * GN + i]);
#pragma unroll
    for (int d = 1; d < 64; d <<= 1) m = fmaxf(m, __shfl_xor(m, d));
    if (lane == 0) stmax[h] = m;
}

// ---------------- Kernel 4: xp -> MFMA B-fragment layout, bf16 hi/lo ----------------
__global__ __launch_bounds__(256) void gat_fragconv(const float* __restrict__ xp,
                                                    short* __restrict__ bh,
                                                    short* __restrict__ bl) {
    const int idx = blockIdx.x * 256 + threadIdx.x;   // (h,t,cf,lane)
    const int lane = idx & 63;
    const int cf = (idx >> 6) & 3;
    const int t = (idx >> 8) & 127;
    const int h = idx >> 15;
    const int g = lane >> 4, c = lane & 15;
    const int col = h * GF + cf * 16 + c;
    const int m0 = t * 32 + g * 8;
    short8v vh, vl;
#pragma unroll
    for (int j = 0; j < 8; ++j) {
        float x = xp[(size_t)(m0 + j) * GHF + col];
        short hi = f2bf(x);
        vh[j] = hi;
        vl[j] = f2bf(x - bf2f(hi));
    }
    ((short8v*)bh)[idx] = vh;
    ((short8v*)bl)[idx] = vl;
}

// ---------------- Kernel 5: flash attention, MFMA, fixed bound, depth-1 prefetch ----------------
// Block = 256 thr = 4 waves, wave w = head blockIdx.y*4+w (r2 structure); 32 q rows; S key-splits.
__global__ __launch_bounds__(256) void gat_attn_mfma(const short* __restrict__ bh,
                                                     const short* __restrict__ bl,
                                                     const float* __restrict__ ss,
                                                     const float* __restrict__ st,
                                                     const float* __restrict__ stmax,
                                                     const float* __restrict__ mask,
                                                     float* __restrict__ acc_p,
                                                     float* __restrict__ l_p,
                                                     int S) {
    const int lane = threadIdx.x & 63;
    const int h = blockIdx.y * 4 + (threadIdx.x >> 6);
    const int q0 = blockIdx.x * 32;
    const int s = blockIdx.z;
    const int TPS = 128 / S;                 // 32-key tiles per split (S<=4 -> TPS even)
    const int g = lane >> 4;

    const int qa = q0 + (lane & 15);
    const int qb = qa + 16;
    const float ssa = ss[h * GN + qa];
    const float ssb = ss[h * GN + qb];
    const float smx = stmax[h];
    const float caL = leaky(ssa + smx) * LOG2E;   // fixed softmax bound (log2 domain)
    const float cbL = leaky(ssb + smx) * LOG2E;

    f32x4 acc[2][4];
#pragma unroll
    for (int qf = 0; qf < 2; ++qf)
#pragma unroll
        for (int cf = 0; cf < 4; ++cf) acc[qf][cf] = (f32x4){0.f, 0.f, 0.f, 0.f};
    float lsa = 0.f, lsb = 0.f;

    const int t0 = s * TPS;
    const float4* stp = (const float4*)&st[h * GN + t0 * 32 + g * 8];
    const float4* mpa = (const float4*)&mask[(size_t)qa * GN + t0 * 32 + g * 8];
    const float4* mpb = (const float4*)&mask[(size_t)qb * GN + t0 * 32 + g * 8];
    const short8v* bhp = (const short8v*)bh + ((size_t)(h * 128 + t0) * 4) * 64 + lane;
    const short8v* blp = (const short8v*)bl + ((size_t)(h * 128 + t0) * 4) * 64 + lane;

    // double-buffered per-tile operands (named regs, static indexing only)
    float4 sA0, sA1, aA0, aA1, bA0, bA1; short8v BhA0, BhA1, BhA2, BhA3, BlA0, BlA1, BlA2, BlA3;
    float4 sB0, sB1, aB0, aB1, bB0, bB1; short8v BhB0, BhB1, BhB2, BhB3, BlB0, BlB1, BlB2, BlB3;

// NOTE: one level of macro indirection so BUF_A/BUF_B expand BEFORE arg matching.
#define LOADT_I(s0,s1,a0,a1,b0,b1,H0,H1,H2,H3,L0,L1,L2,L3) do { \
    s0 = stp[0]; s1 = stp[1]; stp += 8;                        \
    a0 = mpa[0]; a1 = mpa[1]; mpa += 8;                        \
    b0 = mpb[0]; b1 = mpb[1]; mpb += 8;                        \
    H0 = bhp[0]; H1 = bhp[64]; H2 = bhp[128]; H3 = bhp[192]; bhp += 256; \
    L0 = blp[0]; L1 = blp[64]; L2 = blp[128]; L3 = blp[192]; blp += 256; } while (0)
#define LOADT(...) LOADT_I(__VA_ARGS__)

#define COMPUTET_I(s0,s1,a0,a1,b0,b1,H0,H1,H2,H3,L0,L1,L2,L3) do {          \
    float stv[8] = {s0.x, s0.y, s0.z, s0.w, s1.x, s1.y, s1.z, s1.w};        \
    float mav[8] = {a0.x, a0.y, a0.z, a0.w, a1.x, a1.y, a1.z, a1.w};        \
    float mbv[8] = {b0.x, b0.y, b0.z, b0.w, b1.x, b1.y, b1.z, b1.w};        \
    float pa[8], pb[8];                                                     \
    _Pragma("unroll")                                                       \
    for (int j = 0; j < 8; ++j) {                                           \
        float sa = leaky(ssa + stv[j]) + mav[j];                            \
        pa[j] = exp2_hw(fmaf(sa, LOG2E, -caL));                             \
        float sb = leaky(ssb + stv[j]) + mbv[j];                            \
        pb[j] = exp2_hw(fmaf(sb, LOG2E, -cbL));                             \
    }                                                                       \
    _Pragma("unroll")                                                       \
    for (int j = 0; j < 8; ++j) { lsa += pa[j]; lsb += pb[j]; }             \
    union { uint32_t u[4]; short8v v; } Pa, Pb;                             \
    _Pragma("unroll")                                                       \
    for (int w = 0; w < 4; ++w) {                                           \
        Pa.u[w] = cvt_pk_bf16(pa[2 * w], pa[2 * w + 1]);                    \
        Pb.u[w] = cvt_pk_bf16(pb[2 * w], pb[2 * w + 1]);                    \
    }                                                                       \
    acc[0][0] = __builtin_amdgcn_mfma_f32_16x16x32_bf16(Pa.v, H0, acc[0][0], 0, 0, 0); \
    acc[0][0] = __builtin_amdgcn_mfma_f32_16x16x32_bf16(Pa.v, L0, acc[0][0], 0, 0, 0); \
    acc[0][1] = __builtin_amdgcn_mfma_f32_16x16x32_bf16(Pa.v, H1, acc[0][1], 0, 0, 0); \
    acc[0][1] = __builtin_amdgcn_mfma_f32_16x16x32_bf16(Pa.v, L1, acc[0][1], 0, 0, 0); \
    acc[0][2] = __builtin_amdgcn_mfma_f32_16x16x32_bf16(Pa.v, H2, acc[0][2], 0, 0, 0); \
    acc[0][2] = __builtin_amdgcn_mfma_f32_16x16x32_bf16(Pa.v, L2, acc[0][2], 0, 0, 0); \
    acc[0][3] = __builtin_amdgcn_mfma_f32_16x16x32_bf16(Pa.v, H3, acc[0][3], 0, 0, 0); \
    acc[0][3] = __builtin_amdgcn_mfma_f32_16x16x32_bf16(Pa.v, L3, acc[0][3], 0, 0, 0); \
    acc[1][0] = __builtin_amdgcn_mfma_f32_16x16x32_bf16(Pb.v, H0, acc[1][0], 0, 0, 0); \
    acc[1][0] = __builtin_amdgcn_mfma_f32_16x16x32_bf16(Pb.v, L0, acc[1][0], 0, 0, 0); \
    acc[1][1] = __builtin_amdgcn_mfma_f32_16x16x32_bf16(Pb.v, H1, acc[1][1], 0, 0, 0); \
    acc[1][1] = __builtin_amdgcn_mfma_f32_16x16x32_bf16(Pb.v, L1, acc[1][1], 0, 0, 0); \
    acc[1][2] = __builtin_amdgcn_mfma_f32_16x16x32_bf16(Pb.v, H2, acc[1][2], 0, 0, 0); \
    acc[1][2] = __builtin_amdgcn_mfma_f32_16x16x32_bf16(Pb.v, L2, acc[1][2], 0, 0, 0); \
    acc[1][3] = __builtin_amdgcn_mfma_f32_16x16x32_bf16(Pb.v, H3, acc[1][3], 0, 0, 0); \
    acc[1][3] = __builtin_amdgcn_mfma_f32_16x16x32_bf16(Pb.v, L3, acc[1][3], 0, 0, 0); \
    } while (0)
#define COMPUTET(...) COMPUTET_I(__VA_ARGS__)

#define BUF_A sA0, sA1, aA0, aA1, bA0, bA1, BhA0, BhA1, BhA2, BhA3, BlA0, BlA1, BlA2, BlA3
#define BUF_B sB0, sB1, aB0, aB1, bB0, bB1, BhB0, BhB1, BhB2, BhB3, BlB0, BlB1, BlB2, BlB3

    LOADT(BUF_A);                       // tile t0
    for (int t = 0; t + 2 < TPS; t += 2) {
        LOADT(BUF_B);                   // tile t+1 in flight during compute of t
        COMPUTET(BUF_A);
        LOADT(BUF_A);                   // tile t+2 in flight during compute of t+1
        COMPUTET(BUF_B);
    }
    LOADT(BUF_B);                       // last tile (no further prefetch)
    COMPUTET(BUF_A);
    COMPUTET(BUF_B);

#undef LOADT
#undef LOADT_I
#undef COMPUTET
#undef COMPUTET_I
#undef BUF_A
#undef BUF_B

    // partial row-sums: combine the 4 k-groups (lanes l, l^16, l^32, l^48)
    lsa += __shfl_xor(lsa, 16); lsa += __shfl_xor(lsa, 32);
    lsb += __shfl_xor(lsb, 16); lsb += __shfl_xor(lsb, 32);
    if (lane < 16) {
        l_p[(size_t)(s * GH + h) * GN + qa] = lsa;
        l_p[(size_t)(s * GH + h) * GN + qb] = lsb;
    }
    // store partial acc: D layout col=lane&15, row=(lane>>4)*4+r
#pragma unroll
    for (int qf = 0; qf < 2; ++qf)
#pragma unroll
        for (int cf = 0; cf < 4; ++cf)
#pragma unroll
            for (int r = 0; r < 4; ++r) {
                int row = q0 + qf * 16 + (lane >> 4) * 4 + r;
                int col = cf * 16 + (lane & 15);
                acc_p[((size_t)(s * GH + h) * GN + row) * GF + col] = acc[qf][cf][r];
            }
}

// ---------------- Kernel 6: combine splits, head-mean, relu (float4) ----------------
__global__ __launch_bounds__(256) void gat_combine(const float* __restrict__ acc_p,
                                                   const float* __restrict__ l_p,
                                                   float* __restrict__ out, int S) {
    const int idx = blockIdx.x * 256 + threadIdx.x;    // n*16 + f4
    const int n = idx >> 4, f4 = idx & 15;
    const float4* ap = (const float4*)acc_p;
    float4 r = {0.f, 0.f, 0.f, 0.f};
#pragma unroll
    for (int h = 0; h < GH; ++h) {
        float4 a = {0.f, 0.f, 0.f, 0.f};
        float l = 0.f;
        for (int s = 0; s < S; ++s) {
            float4 v = ap[((size_t)(s * GH + h) * GN + n) * 16 + f4];
            a.x += v.x; a.y += v.y; a.z += v.z; a.w += v.w;
            l += l_p[(size_t)(s * GH + h) * GN + n];
        }
        float il = 1.0f / l;
        r.x += a.x * il; r.y += a.y * il; r.z += a.z * il; r.w += a.w * il;
    }
    float4 o;
    o.x = fmaxf(r.x * 0.125f, 0.f);
    o.y = fmaxf(r.y * 0.125f, 0.f);
    o.z = fmaxf(r.z * 0.125f, 0.f);
    o.w = fmaxf(r.w * 0.125f, 0.f);
    ((float4*)out)[idx] = o;
}

extern "C" void kernel_launch(void* const* d_in, const int* in_sizes, int n_in,
                              void* d_out, int out_size, void* d_ws, size_t ws_size,
                              hipStream_t stream) {
    const float* A     = (const float*)d_in[0];
    const float* mask  = (const float*)d_in[1];
    const float* Wp    = (const float*)d_in[2];
    const float* a_src = (const float*)d_in[3];
    const float* a_tgt = (const float*)d_in[4];
    float* out = (float*)d_out;

    char* w = (char*)d_ws;
    float* xp    = (float*)w;              w += (size_t)GN * GHF * 4;        // 8 MB
    float* ss    = (float*)w;              w += (size_t)GH * GN * 4;
    float* st    = (float*)w;              w += (size_t)GH * GN * 4;
    float* stmx  = (float*)w;              w += 256;
    short* bh    = (short*)w;              w += (size_t)GH * 128 * 4 * 64 * 8 * 2; // 4 MB
    short* bl    = (short*)w;              w += (size_t)GH * 128 * 4 * 64 * 8 * 2; // 4 MB
    size_t base = (size_t)(w - (char*)d_ws);
    size_t per_s = (size_t)GH * GN * GF * 4 + (size_t)GH * GN * 4;           // 8.5 MB
    int S = 4;
    while (S > 1 && base + (size_t)S * per_s > ws_size) S >>= 1;
    float* acc_p = (float*)w;              w += (size_t)S * GH * GN * GF * 4;
    float* l_p   = (float*)w;

    gat_proj<<<dim3(GN / 64, GHF / 64), 256, 0, stream>>>(A, Wp, xp);
    gat_scores<<<(GH * GN) / 4, 256, 0, stream>>>(xp, a_src, a_tgt, ss, st);
    gat_stmax<<<1, 512, 0, stream>>>(st, stmx);
    gat_fragconv<<<(GH * 128 * 4 * 64) / 256, 256, 0, stream>>>(xp, bh, bl);
    gat_attn_mfma<<<dim3(GN / 32, 2, S), 256, 0, stream>>>(bh, bl, ss, st, stmx, mask,
                                                           acc_p, l_p, S);
    gat_combine<<<(GN * 16) / 256, 256, 0, stream>>>(acc_p, l_p, out, S);
}

// Round 7
// 120.315 us; speedup vs baseline: 1.5343x; 1.2526x over previous
//
#include <hip/hip_runtime.h>
#include <hip/hip_bf16.h>
#include <cstdint>

#define GN 4096      // N nodes
#define GIN 128      // IN_F
#define GF 64        // OUT_F
#define GH 8         // heads
#define GHF (GH*GF)  // 512
#define LOG2E 1.4426950408889634f

typedef __attribute__((ext_vector_type(8))) short short8v;
typedef __attribute__((ext_vector_type(4))) float f32x4;

__device__ __forceinline__ short f2bf(float x) {           // RNE float->bf16
    uint32_t u = __float_as_uint(x);
    uint32_t r = u + 0x7fffu + ((u >> 16) & 1u);
    return (short)(r >> 16);
}
__device__ __forceinline__ float bf2f(short h) {
    return __uint_as_float(((uint32_t)(unsigned short)h) << 16);
}
__device__ __forceinline__ float leaky(float t) { return fmaxf(t, 0.2f * t); }
__device__ __forceinline__ uint32_t cvt_pk_bf16(float lo, float hi) {
    uint32_t r;
    asm("v_cvt_pk_bf16_f32 %0, %1, %2" : "=v"(r) : "v"(lo), "v"(hi));
    return r;
}

// ---------------- Kernel 0a/0b: mask zero-detection (exact) ----------------
__global__ void gat_zeroflag(uint32_t* __restrict__ f) {
    if (threadIdx.x == 0 && blockIdx.x == 0) f[0] = 0u;
}
__global__ __launch_bounds__(256) void gat_maskscan(const uint32_t* __restrict__ m,
                                                    uint32_t* __restrict__ flag) {
    uint32_t acc = 0;
    const uint4* m4 = (const uint4*)m;
    const int total = (GN * GN) / 4;           // uint4 count
    for (int i = blockIdx.x * 256 + threadIdx.x; i < total; i += gridDim.x * 256) {
        uint4 v = m4[i];
        acc |= v.x | v.y | v.z | v.w;
    }
#pragma unroll
    for (int d = 1; d < 64; d <<= 1) acc |= (uint32_t)__shfl_xor((int)acc, d);
    __shared__ uint32_t wred[4];
    if ((threadIdx.x & 63) == 0) wred[threadIdx.x >> 6] = acc;
    __syncthreads();
    if (threadIdx.x == 0) {
        uint32_t a = wred[0] | wred[1] | wred[2] | wred[3];
        if (a) atomicOr(flag, 1u);
    }
}

// ---------------- Kernel 1: projection xp = A @ Wp^T (fp32) ----------------
__global__ __launch_bounds__(256) void gat_proj(const float* __restrict__ A,
                                                const float* __restrict__ W,
                                                float* __restrict__ xp) {
    __shared__ float As[64][129];
    __shared__ float Ws[64][129];
    const int n0 = blockIdx.x * 64;
    const int j0 = blockIdx.y * 64;
    const int tid = threadIdx.x;
    const float4* A4 = (const float4*)A;
    const float4* W4 = (const float4*)W;
#pragma unroll
    for (int i = 0; i < 8; ++i) {
        int idx = tid + i * 256;
        int r = idx >> 5, c4 = idx & 31;
        float4 v = A4[(size_t)(n0 + r) * 32 + c4];
        As[r][c4 * 4 + 0] = v.x; As[r][c4 * 4 + 1] = v.y;
        As[r][c4 * 4 + 2] = v.z; As[r][c4 * 4 + 3] = v.w;
        float4 w = W4[(size_t)(j0 + r) * 32 + c4];
        Ws[r][c4 * 4 + 0] = w.x; Ws[r][c4 * 4 + 1] = w.y;
        Ws[r][c4 * 4 + 2] = w.z; Ws[r][c4 * 4 + 3] = w.w;
    }
    __syncthreads();
    const int tx = tid & 15, ty = tid >> 4;
    float acc[4][4] = {};
    for (int k = 0; k < 128; ++k) {
        float a[4], b[4];
#pragma unroll
        for (int i = 0; i < 4; ++i) { a[i] = As[ty * 4 + i][k]; b[i] = Ws[tx * 4 + i][k]; }
#pragma unroll
        for (int i = 0; i < 4; ++i)
#pragma unroll
            for (int j = 0; j < 4; ++j) acc[i][j] = fmaf(a[i], b[j], acc[i][j]);
    }
#pragma unroll
    for (int i = 0; i < 4; ++i)
#pragma unroll
        for (int j = 0; j < 4; ++j)
            xp[(size_t)(n0 + ty * 4 + i) * GHF + (j0 + tx * 4 + j)] = acc[i][j];
}

// ---------------- Kernel 2: ss/st ----------------
__global__ __launch_bounds__(256) void gat_scores(const float* __restrict__ xp,
                                                  const float* __restrict__ a_src,
                                                  const float* __restrict__ a_tgt,
                                                  float* __restrict__ ss,
                                                  float* __restrict__ st) {
    const int lane = threadIdx.x & 63;
    const int w = threadIdx.x >> 6;
    const int r = blockIdx.x * 4 + w;
    const int h = r >> 12;
    const int n = r & 4095;
    float x = xp[(size_t)n * GHF + h * GF + lane];
    float s1 = x * a_src[h * GF + lane];
    float s2 = x * a_tgt[h * GF + lane];
#pragma unroll
    for (int d = 1; d < 64; d <<= 1) {
        s1 += __shfl_xor(s1, d);
        s2 += __shfl_xor(s2, d);
    }
    if (lane == 0) {
        ss[h * GN + n] = s1;
        st[h * GN + n] = s2;
    }
}

// ---------------- Kernel 3: stmax[h] = max_n st[h][n] ----------------
__global__ __launch_bounds__(512) void gat_stmax(const float* __restrict__ st,
                                                 float* __restrict__ stmax) {
    const int h = threadIdx.x >> 6;
    const int lane = threadIdx.x & 63;
    float m = -1e30f;
    for (int i = lane; i < GN; i += 64) m = fmaxf(m, st[h * GN + i]);
#pragma unroll
    for (int d = 1; d < 64; d <<= 1) m = fmaxf(m, __shfl_xor(m, d));
    if (lane == 0) stmax[h] = m;
}

// ---------------- Kernel 4: xp -> MFMA B-fragment layout, bf16 hi/lo ----------------
__global__ __launch_bounds__(256) void gat_fragconv(const float* __restrict__ xp,
                                                    short* __restrict__ bh,
                                                    short* __restrict__ bl) {
    const int idx = blockIdx.x * 256 + threadIdx.x;   // (h,t,cf,lane)
    const int lane = idx & 63;
    const int cf = (idx >> 6) & 3;
    const int t = (idx >> 8) & 127;
    const int h = idx >> 15;
    const int g = lane >> 4, c = lane & 15;
    const int col = h * GF + cf * 16 + c;
    const int m0 = t * 32 + g * 8;
    short8v vh, vl;
#pragma unroll
    for (int j = 0; j < 8; ++j) {
        float x = xp[(size_t)(m0 + j) * GHF + col];
        short hi = f2bf(x);
        vh[j] = hi;
        vl[j] = f2bf(x - bf2f(hi));
    }
    ((short8v*)bh)[idx] = vh;
    ((short8v*)bl)[idx] = vl;
}

// ---------------- attn pipeline (r5-proven schedule), templated on mask presence ----------------
template<bool HM>
__device__ __forceinline__ void attn_pipeline(const float4* stp, const float4* mpa,
                                              const float4* mpb, const short8v* bhp,
                                              const short8v* blp, int TPS,
                                              float ssa, float ssb, float caL, float cbL,
                                              f32x4 (&acc)[2][4], float& lsa, float& lsb) {
    // double-buffered per-tile operands (named regs, static indexing only)
    float4 sA0, sA1, aA0, aA1, bA0, bA1; short8v BhA0, BhA1, BhA2, BhA3, BlA0, BlA1, BlA2, BlA3;
    float4 sB0, sB1, aB0, aB1, bB0, bB1; short8v BhB0, BhB1, BhB2, BhB3, BlB0, BlB1, BlB2, BlB3;

// NOTE: one level of macro indirection so BUF_A/BUF_B expand BEFORE arg matching.
#define LOADT_I(s0,s1,a0,a1,b0,b1,H0,H1,H2,H3,L0,L1,L2,L3) do { \
    s0 = stp[0]; s1 = stp[1]; stp += 8;                        \
    if constexpr (HM) { a0 = mpa[0]; a1 = mpa[1]; b0 = mpb[0]; b1 = mpb[1]; } \
    mpa += 8; mpb += 8;                                        \
    H0 = bhp[0]; H1 = bhp[64]; H2 = bhp[128]; H3 = bhp[192]; bhp += 256; \
    L0 = blp[0]; L1 = blp[64]; L2 = blp[128]; L3 = blp[192]; blp += 256; } while (0)
#define LOADT(...) LOADT_I(__VA_ARGS__)

#define COMPUTET_I(s0,s1,a0,a1,b0,b1,H0,H1,H2,H3,L0,L1,L2,L3) do {          \
    float stv[8] = {s0.x, s0.y, s0.z, s0.w, s1.x, s1.y, s1.z, s1.w};        \
    float mav[8], mbv[8];                                                   \
    if constexpr (HM) {                                                     \
        mav[0]=a0.x; mav[1]=a0.y; mav[2]=a0.z; mav[3]=a0.w;                 \
        mav[4]=a1.x; mav[5]=a1.y; mav[6]=a1.z; mav[7]=a1.w;                 \
        mbv[0]=b0.x; mbv[1]=b0.y; mbv[2]=b0.z; mbv[3]=b0.w;                 \
        mbv[4]=b1.x; mbv[5]=b1.y; mbv[6]=b1.z; mbv[7]=b1.w;                 \
    }                                                                       \
    float pa[8], pb[8];                                                     \
    _Pragma("unroll")                                                       \
    for (int j = 0; j < 8; ++j) {                                           \
        float sa = leaky(ssa + stv[j]);                                     \
        if constexpr (HM) sa += mav[j];                                     \
        pa[j] = __builtin_amdgcn_exp2f(fmaf(sa, LOG2E, -caL));              \
        float sb = leaky(ssb + stv[j]);                                     \
        if constexpr (HM) sb += mbv[j];                                     \
        pb[j] = __builtin_amdgcn_exp2f(fmaf(sb, LOG2E, -cbL));              \
    }                                                                       \
    _Pragma("unroll")                                                       \
    for (int j = 0; j < 8; ++j) { lsa += pa[j]; lsb += pb[j]; }             \
    union { uint32_t u[4]; short8v v; } Pa, Pb;                             \
    _Pragma("unroll")                                                       \
    for (int w = 0; w < 4; ++w) {                                           \
        Pa.u[w] = cvt_pk_bf16(pa[2 * w], pa[2 * w + 1]);                    \
        Pb.u[w] = cvt_pk_bf16(pb[2 * w], pb[2 * w + 1]);                    \
    }                                                                       \
    acc[0][0] = __builtin_amdgcn_mfma_f32_16x16x32_bf16(Pa.v, H0, acc[0][0], 0, 0, 0); \
    acc[0][0] = __builtin_amdgcn_mfma_f32_16x16x32_bf16(Pa.v, L0, acc[0][0], 0, 0, 0); \
    acc[0][1] = __builtin_amdgcn_mfma_f32_16x16x32_bf16(Pa.v, H1, acc[0][1], 0, 0, 0); \
    acc[0][1] = __builtin_amdgcn_mfma_f32_16x16x32_bf16(Pa.v, L1, acc[0][1], 0, 0, 0); \
    acc[0][2] = __builtin_amdgcn_mfma_f32_16x16x32_bf16(Pa.v, H2, acc[0][2], 0, 0, 0); \
    acc[0][2] = __builtin_amdgcn_mfma_f32_16x16x32_bf16(Pa.v, L2, acc[0][2], 0, 0, 0); \
    acc[0][3] = __builtin_amdgcn_mfma_f32_16x16x32_bf16(Pa.v, H3, acc[0][3], 0, 0, 0); \
    acc[0][3] = __builtin_amdgcn_mfma_f32_16x16x32_bf16(Pa.v, L3, acc[0][3], 0, 0, 0); \
    acc[1][0] = __builtin_amdgcn_mfma_f32_16x16x32_bf16(Pb.v, H0, acc[1][0], 0, 0, 0); \
    acc[1][0] = __builtin_amdgcn_mfma_f32_16x16x32_bf16(Pb.v, L0, acc[1][0], 0, 0, 0); \
    acc[1][1] = __builtin_amdgcn_mfma_f32_16x16x32_bf16(Pb.v, H1, acc[1][1], 0, 0, 0); \
    acc[1][1] = __builtin_amdgcn_mfma_f32_16x16x32_bf16(Pb.v, L1, acc[1][1], 0, 0, 0); \
    acc[1][2] = __builtin_amdgcn_mfma_f32_16x16x32_bf16(Pb.v, H2, acc[1][2], 0, 0, 0); \
    acc[1][2] = __builtin_amdgcn_mfma_f32_16x16x32_bf16(Pb.v, L2, acc[1][2], 0, 0, 0); \
    acc[1][3] = __builtin_amdgcn_mfma_f32_16x16x32_bf16(Pb.v, H3, acc[1][3], 0, 0, 0); \
    acc[1][3] = __builtin_amdgcn_mfma_f32_16x16x32_bf16(Pb.v, L3, acc[1][3], 0, 0, 0); \
    } while (0)
#define COMPUTET(...) COMPUTET_I(__VA_ARGS__)

#define BUF_A sA0, sA1, aA0, aA1, bA0, bA1, BhA0, BhA1, BhA2, BhA3, BlA0, BlA1, BlA2, BlA3
#define BUF_B sB0, sB1, aB0, aB1, bB0, bB1, BhB0, BhB1, BhB2, BhB3, BlB0, BlB1, BlB2, BlB3

    LOADT(BUF_A);                       // tile t0
    for (int t = 0; t + 2 < TPS; t += 2) {
        LOADT(BUF_B);                   // tile t+1 in flight during compute of t
        COMPUTET(BUF_A);
        LOADT(BUF_A);                   // tile t+2 in flight during compute of t+1
        COMPUTET(BUF_B);
    }
    LOADT(BUF_B);                       // last tile (no further prefetch)
    COMPUTET(BUF_A);
    COMPUTET(BUF_B);

#undef LOADT
#undef LOADT_I
#undef COMPUTET
#undef COMPUTET_I
#undef BUF_A
#undef BUF_B
}

// ---------------- Kernel 5: flash attention, MFMA, fixed bound, depth-1 prefetch ----------------
// Block = 256 thr = 4 waves, wave w = head blockIdx.y*4+w (r5-proven geometry); 32 q rows; S key-splits.
__global__ __launch_bounds__(256) void gat_attn_mfma(const short* __restrict__ bh,
                                                     const short* __restrict__ bl,
                                                     const float* __restrict__ ss,
                                                     const float* __restrict__ st,
                                                     const float* __restrict__ stmax,
                                                     const float* __restrict__ mask,
                                                     const uint32_t* __restrict__ mflag,
                                                     float* __restrict__ acc_p,
                                                     float* __restrict__ l_p,
                                                     int S) {
    const int lane = threadIdx.x & 63;
    const int h = blockIdx.y * 4 + (threadIdx.x >> 6);
    const int q0 = blockIdx.x * 32;
    const int s = blockIdx.z;
    const int TPS = 128 / S;                 // 32-key tiles per split (S<=4 -> TPS even)
    const int g = lane >> 4;

    const int qa = q0 + (lane & 15);
    const int qb = qa + 16;
    const float ssa = ss[h * GN + qa];
    const float ssb = ss[h * GN + qb];
    const float smx = stmax[h];
    const float caL = leaky(ssa + smx) * LOG2E;   // fixed softmax bound (log2 domain)
    const float cbL = leaky(ssb + smx) * LOG2E;

    f32x4 acc[2][4];
#pragma unroll
    for (int qf = 0; qf < 2; ++qf)
#pragma unroll
        for (int cf = 0; cf < 4; ++cf) acc[qf][cf] = (f32x4){0.f, 0.f, 0.f, 0.f};
    float lsa = 0.f, lsb = 0.f;

    const int t0 = s * TPS;
    const float4* stp = (const float4*)&st[h * GN + t0 * 32 + g * 8];
    const float4* mpa = (const float4*)&mask[(size_t)qa * GN + t0 * 32 + g * 8];
    const float4* mpb = (const float4*)&mask[(size_t)qb * GN + t0 * 32 + g * 8];
    const short8v* bhp = (const short8v*)bh + ((size_t)(h * 128 + t0) * 4) * 64 + lane;
    const short8v* blp = (const short8v*)bl + ((size_t)(h * 128 + t0) * 4) * 64 + lane;

    if (mflag[0] != 0u)
        attn_pipeline<true >(stp, mpa, mpb, bhp, blp, TPS, ssa, ssb, caL, cbL, acc, lsa, lsb);
    else
        attn_pipeline<false>(stp, mpa, mpb, bhp, blp, TPS, ssa, ssb, caL, cbL, acc, lsa, lsb);

    // partial row-sums: combine the 4 k-groups (lanes l, l^16, l^32, l^48)
    lsa += __shfl_xor(lsa, 16); lsa += __shfl_xor(lsa, 32);
    lsb += __shfl_xor(lsb, 16); lsb += __shfl_xor(lsb, 32);
    if (lane < 16) {
        l_p[(size_t)(s * GH + h) * GN + qa] = lsa;
        l_p[(size_t)(s * GH + h) * GN + qb] = lsb;
    }
    // store partial acc: D layout col=lane&15, row=(lane>>4)*4+r
#pragma unroll
    for (int qf = 0; qf < 2; ++qf)
#pragma unroll
        for (int cf = 0; cf < 4; ++cf)
#pragma unroll
            for (int r = 0; r < 4; ++r) {
                int row = q0 + qf * 16 + (lane >> 4) * 4 + r;
                int col = cf * 16 + (lane & 15);
                acc_p[((size_t)(s * GH + h) * GN + row) * GF + col] = acc[qf][cf][r];
            }
}

// ---------------- Kernel 6: combine splits, head-mean, relu (float4) ----------------
__global__ __launch_bounds__(256) void gat_combine(const float* __restrict__ acc_p,
                                                   const float* __restrict__ l_p,
                                                   float* __restrict__ out, int S) {
    const int idx = blockIdx.x * 256 + threadIdx.x;    // n*16 + f4
    const int n = idx >> 4, f4 = idx & 15;
    const float4* ap = (const float4*)acc_p;
    float4 r = {0.f, 0.f, 0.f, 0.f};
#pragma unroll
    for (int h = 0; h < GH; ++h) {
        float4 a = {0.f, 0.f, 0.f, 0.f};
        float l = 0.f;
        for (int s = 0; s < S; ++s) {
            float4 v = ap[((size_t)(s * GH + h) * GN + n) * 16 + f4];
            a.x += v.x; a.y += v.y; a.z += v.z; a.w += v.w;
            l += l_p[(size_t)(s * GH + h) * GN + n];
        }
        float il = 1.0f / l;
        r.x += a.x * il; r.y += a.y * il; r.z += a.z * il; r.w += a.w * il;
    }
    float4 o;
    o.x = fmaxf(r.x * 0.125f, 0.f);
    o.y = fmaxf(r.y * 0.125f, 0.f);
    o.z = fmaxf(r.z * 0.125f, 0.f);
    o.w = fmaxf(r.w * 0.125f, 0.f);
    ((float4*)out)[idx] = o;
}

extern "C" void kernel_launch(void* const* d_in, const int* in_sizes, int n_in,
                              void* d_out, int out_size, void* d_ws, size_t ws_size,
                              hipStream_t stream) {
    const float* A     = (const float*)d_in[0];
    const float* mask  = (const float*)d_in[1];
    const float* Wp    = (const float*)d_in[2];
    const float* a_src = (const float*)d_in[3];
    const float* a_tgt = (const float*)d_in[4];
    float* out = (float*)d_out;

    char* w = (char*)d_ws;
    float* xp    = (float*)w;              w += (size_t)GN * GHF * 4;        // 8 MB
    float* ss    = (float*)w;              w += (size_t)GH * GN * 4;
    float* st    = (float*)w;              w += (size_t)GH * GN * 4;
    float* stmx  = (float*)w;              w += 256;
    uint32_t* mflag = (uint32_t*)w;        w += 256;
    short* bh    = (short*)w;              w += (size_t)GH * 128 * 4 * 64 * 8 * 2; // 4 MB
    short* bl    = (short*)w;              w += (size_t)GH * 128 * 4 * 64 * 8 * 2; // 4 MB
    size_t base = (size_t)(w - (char*)d_ws);
    size_t per_s = (size_t)GH * GN * GF * 4 + (size_t)GH * GN * 4;           // 8.5 MB
    int S = 4;
    while (S > 1 && base + (size_t)S * per_s > ws_size) S >>= 1;
    float* acc_p = (float*)w;              w += (size_t)S * GH * GN * GF * 4;
    float* l_p   = (float*)w;

    gat_zeroflag<<<1, 64, 0, stream>>>(mflag);
    gat_maskscan<<<2048, 256, 0, stream>>>((const uint32_t*)mask, mflag);
    gat_proj<<<dim3(GN / 64, GHF / 64), 256, 0, stream>>>(A, Wp, xp);
    gat_scores<<<(GH * GN) / 4, 256, 0, stream>>>(xp, a_src, a_tgt, ss, st);
    gat_stmax<<<1, 512, 0, stream>>>(st, stmx);
    gat_fragconv<<<(GH * 128 * 4 * 64) / 256, 256, 0, stream>>>(xp, bh, bl);
    gat_attn_mfma<<<dim3(GN / 32, 2, S), 256, 0, stream>>>(bh, bl, ss, st, stmx, mask,
                                                           mflag, acc_p, l_p, S);
    gat_combine<<<(GN * 16) / 256, 256, 0, stream>>>(acc_p, l_p, out, S);
}

// Round 8
// 102.757 us; speedup vs baseline: 1.7965x; 1.1709x over previous
//
#include <hip/hip_runtime.h>
#include <hip/hip_bf16.h>
#include <cstdint>

#define GN 4096      // N nodes
#define GIN 128      // IN_F
#define GF 64        // OUT_F
#define GH 8         // heads
#define GHF (GH*GF)  // 512
#define LOG2E 1.4426950408889634f

typedef __attribute__((ext_vector_type(8))) short short8v;
typedef __attribute__((ext_vector_type(4))) float f32x4;

__device__ __forceinline__ short f2bf(float x) {           // RNE float->bf16
    uint32_t u = __float_as_uint(x);
    uint32_t r = u + 0x7fffu + ((u >> 16) & 1u);
    return (short)(r >> 16);
}
__device__ __forceinline__ float leaky(float t) { return fmaxf(t, 0.2f * t); }
__device__ __forceinline__ uint32_t cvt_pk_bf16(float lo, float hi) {
    uint32_t r;
    asm("v_cvt_pk_bf16_f32 %0, %1, %2" : "=v"(r) : "v"(lo), "v"(hi));
    return r;
}

// ---------------- Kernel 0a/0b: mask zero-detection (exact) ----------------
__global__ void gat_zeroflag(uint32_t* __restrict__ f) {
    if (threadIdx.x == 0 && blockIdx.x == 0) f[0] = 0u;
}
__global__ __launch_bounds__(256) void gat_maskscan(const uint32_t* __restrict__ m,
                                                    uint32_t* __restrict__ flag) {
    uint32_t acc = 0;
    const uint4* m4 = (const uint4*)m;
    const int total = (GN * GN) / 4;           // uint4 count
    for (int i = blockIdx.x * 256 + threadIdx.x; i < total; i += gridDim.x * 256) {
        uint4 v = m4[i];
        acc |= v.x | v.y | v.z | v.w;
    }
#pragma unroll
    for (int d = 1; d < 64; d <<= 1) acc |= (uint32_t)__shfl_xor((int)acc, d);
    __shared__ uint32_t wred[4];
    if ((threadIdx.x & 63) == 0) wred[threadIdx.x >> 6] = acc;
    __syncthreads();
    if (threadIdx.x == 0) {
        uint32_t a = wred[0] | wred[1] | wred[2] | wred[3];
        if (a) atomicOr(flag, 1u);
    }
}

// ---------------- Kernel 1: projection xp = A @ Wp^T (fp32) ----------------
__global__ __launch_bounds__(256) void gat_proj(const float* __restrict__ A,
                                                const float* __restrict__ W,
                                                float* __restrict__ xp) {
    __shared__ float As[64][129];
    __shared__ float Ws[64][129];
    const int n0 = blockIdx.x * 64;
    const int j0 = blockIdx.y * 64;
    const int tid = threadIdx.x;
    const float4* A4 = (const float4*)A;
    const float4* W4 = (const float4*)W;
#pragma unroll
    for (int i = 0; i < 8; ++i) {
        int idx = tid + i * 256;
        int r = idx >> 5, c4 = idx & 31;
        float4 v = A4[(size_t)(n0 + r) * 32 + c4];
        As[r][c4 * 4 + 0] = v.x; As[r][c4 * 4 + 1] = v.y;
        As[r][c4 * 4 + 2] = v.z; As[r][c4 * 4 + 3] = v.w;
        float4 w = W4[(size_t)(j0 + r) * 32 + c4];
        Ws[r][c4 * 4 + 0] = w.x; Ws[r][c4 * 4 + 1] = w.y;
        Ws[r][c4 * 4 + 2] = w.z; Ws[r][c4 * 4 + 3] = w.w;
    }
    __syncthreads();
    const int tx = tid & 15, ty = tid >> 4;
    float acc[4][4] = {};
    for (int k = 0; k < 128; ++k) {
        float a[4], b[4];
#pragma unroll
        for (int i = 0; i < 4; ++i) { a[i] = As[ty * 4 + i][k]; b[i] = Ws[tx * 4 + i][k]; }
#pragma unroll
        for (int i = 0; i < 4; ++i)
#pragma unroll
            for (int j = 0; j < 4; ++j) acc[i][j] = fmaf(a[i], b[j], acc[i][j]);
    }
#pragma unroll
    for (int i = 0; i < 4; ++i)
#pragma unroll
        for (int j = 0; j < 4; ++j)
            xp[(size_t)(n0 + ty * 4 + i) * GHF + (j0 + tx * 4 + j)] = acc[i][j];
}

// ---------------- Kernel 2: ss/st ----------------
__global__ __launch_bounds__(256) void gat_scores(const float* __restrict__ xp,
                                                  const float* __restrict__ a_src,
                                                  const float* __restrict__ a_tgt,
                                                  float* __restrict__ ss,
                                                  float* __restrict__ st) {
    const int lane = threadIdx.x & 63;
    const int w = threadIdx.x >> 6;
    const int r = blockIdx.x * 4 + w;
    const int h = r >> 12;
    const int n = r & 4095;
    float x = xp[(size_t)n * GHF + h * GF + lane];
    float s1 = x * a_src[h * GF + lane];
    float s2 = x * a_tgt[h * GF + lane];
#pragma unroll
    for (int d = 1; d < 64; d <<= 1) {
        s1 += __shfl_xor(s1, d);
        s2 += __shfl_xor(s2, d);
    }
    if (lane == 0) {
        ss[h * GN + n] = s1;
        st[h * GN + n] = s2;
    }
}

// ---------------- Kernel 3: stmax[h] = max_n st[h][n] (one block per head) ----------------
__global__ __launch_bounds__(256) void gat_stmax(const float* __restrict__ st,
                                                 float* __restrict__ stmax) {
    const int h = blockIdx.x;
    const int tid = threadIdx.x;
    float m = -1e30f;
    for (int i = tid; i < GN; i += 256) m = fmaxf(m, st[h * GN + i]);
#pragma unroll
    for (int d = 1; d < 64; d <<= 1) m = fmaxf(m, __shfl_xor(m, d));
    __shared__ float wred[4];
    if ((tid & 63) == 0) wred[tid >> 6] = m;
    __syncthreads();
    if (tid == 0)
        stmax[h] = fmaxf(fmaxf(wred[0], wred[1]), fmaxf(wred[2], wred[3]));
}

// ---------------- Kernel 4: xp -> MFMA B-fragment layout, bf16 (hi only) ----------------
__global__ __launch_bounds__(256) void gat_fragconv(const float* __restrict__ xp,
                                                    short* __restrict__ bh) {
    const int idx = blockIdx.x * 256 + threadIdx.x;   // (h,t,cf,lane)
    const int lane = idx & 63;
    const int cf = (idx >> 6) & 3;
    const int t = (idx >> 8) & 127;
    const int h = idx >> 15;
    const int g = lane >> 4, c = lane & 15;
    const int col = h * GF + cf * 16 + c;
    const int m0 = t * 32 + g * 8;
    short8v vh;
#pragma unroll
    for (int j = 0; j < 8; ++j)
        vh[j] = f2bf(xp[(size_t)(m0 + j) * GHF + col]);
    ((short8v*)bh)[idx] = vh;
}

// ---------------- attn pipeline (depth-1 reg prefetch), templated on mask presence ----------------
template<bool HM>
__device__ __forceinline__ void attn_pipeline(const float4* stp, const float4* mpa,
                                              const float4* mpb, const short8v* bhp,
                                              int TPS, float KaP, float KaN,
                                              float KbP, float KbN,
                                              f32x4 (&acc)[2][4], f32x4& accLa, f32x4& accLb) {
    const short BONE = (short)0x3F80;            // bf16 1.0
    const short8v BONES = {BONE, BONE, BONE, BONE, BONE, BONE, BONE, BONE};

    // double-buffered per-tile operands (named regs, static indexing only)
    float4 sA0, sA1, aA0, aA1, bA0, bA1; short8v BhA0, BhA1, BhA2, BhA3;
    float4 sB0, sB1, aB0, aB1, bB0, bB1; short8v BhB0, BhB1, BhB2, BhB3;

// NOTE: one level of macro indirection so BUF_A/BUF_B expand BEFORE arg matching.
#define LOADT_I(s0,s1,a0,a1,b0,b1,H0,H1,H2,H3) do { \
    s0 = stp[0]; s1 = stp[1]; stp += 8;                        \
    if constexpr (HM) { a0 = mpa[0]; a1 = mpa[1]; b0 = mpb[0]; b1 = mpb[1]; mpa += 8; mpb += 8; } \
    H0 = bhp[0]; H1 = bhp[64]; H2 = bhp[128]; H3 = bhp[192]; bhp += 256; } while (0)
#define LOADT(...) LOADT_I(__VA_ARGS__)

#define COMPUTET_I(s0,s1,a0,a1,b0,b1,H0,H1,H2,H3) do {                      \
    float stv[8] = {s0.x, s0.y, s0.z, s0.w, s1.x, s1.y, s1.z, s1.w};        \
    float mav[8], mbv[8];                                                   \
    if constexpr (HM) {                                                     \
        mav[0]=a0.x; mav[1]=a0.y; mav[2]=a0.z; mav[3]=a0.w;                 \
        mav[4]=a1.x; mav[5]=a1.y; mav[6]=a1.z; mav[7]=a1.w;                 \
        mbv[0]=b0.x; mbv[1]=b0.y; mbv[2]=b0.z; mbv[3]=b0.w;                 \
        mbv[4]=b1.x; mbv[5]=b1.y; mbv[6]=b1.z; mbv[7]=b1.w;                 \
    }                                                                       \
    float pa[8], pb[8];                                                     \
    _Pragma("unroll")                                                       \
    for (int j = 0; j < 8; ++j) {                                           \
        float stvL = stv[j] * LOG2E;                                        \
        float ea = fmaxf(stvL + KaP, fmaf(stvL, 0.2f, KaN));                \
        float eb = fmaxf(stvL + KbP, fmaf(stvL, 0.2f, KbN));                \
        if constexpr (HM) { ea = fmaf(mav[j], LOG2E, ea); eb = fmaf(mbv[j], LOG2E, eb); } \
        pa[j] = __builtin_amdgcn_exp2f(ea);                                 \
        pb[j] = __builtin_amdgcn_exp2f(eb);                                 \
    }                                                                       \
    union { uint32_t u[4]; short8v v; } Pa, Pb;                             \
    _Pragma("unroll")                                                       \
    for (int w = 0; w < 4; ++w) {                                           \
        Pa.u[w] = cvt_pk_bf16(pa[2 * w], pa[2 * w + 1]);                    \
        Pb.u[w] = cvt_pk_bf16(pb[2 * w], pb[2 * w + 1]);                    \
    }                                                                       \
    acc[0][0] = __builtin_amdgcn_mfma_f32_16x16x32_bf16(Pa.v, H0, acc[0][0], 0, 0, 0); \
    acc[0][1] = __builtin_amdgcn_mfma_f32_16x16x32_bf16(Pa.v, H1, acc[0][1], 0, 0, 0); \
    acc[0][2] = __builtin_amdgcn_mfma_f32_16x16x32_bf16(Pa.v, H2, acc[0][2], 0, 0, 0); \
    acc[0][3] = __builtin_amdgcn_mfma_f32_16x16x32_bf16(Pa.v, H3, acc[0][3], 0, 0, 0); \
    acc[1][0] = __builtin_amdgcn_mfma_f32_16x16x32_bf16(Pb.v, H0, acc[1][0], 0, 0, 0); \
    acc[1][1] = __builtin_amdgcn_mfma_f32_16x16x32_bf16(Pb.v, H1, acc[1][1], 0, 0, 0); \
    acc[1][2] = __builtin_amdgcn_mfma_f32_16x16x32_bf16(Pb.v, H2, acc[1][2], 0, 0, 0); \
    acc[1][3] = __builtin_amdgcn_mfma_f32_16x16x32_bf16(Pb.v, H3, acc[1][3], 0, 0, 0); \
    accLa = __builtin_amdgcn_mfma_f32_16x16x32_bf16(Pa.v, BONES, accLa, 0, 0, 0); \
    accLb = __builtin_amdgcn_mfma_f32_16x16x32_bf16(Pb.v, BONES, accLb, 0, 0, 0); \
    } while (0)
#define COMPUTET(...) COMPUTET_I(__VA_ARGS__)

#define BUF_A sA0, sA1, aA0, aA1, bA0, bA1, BhA0, BhA1, BhA2, BhA3
#define BUF_B sB0, sB1, aB0, aB1, bB0, bB1, BhB0, BhB1, BhB2, BhB3

    LOADT(BUF_A);                       // tile t0
    for (int t = 0; t + 2 < TPS; t += 2) {
        LOADT(BUF_B);                   // tile t+1 in flight during compute of t
        COMPUTET(BUF_A);
        LOADT(BUF_A);                   // tile t+2 in flight during compute of t+1
        COMPUTET(BUF_B);
    }
    LOADT(BUF_B);                       // last tile (no further prefetch)
    COMPUTET(BUF_A);
    COMPUTET(BUF_B);

#undef LOADT
#undef LOADT_I
#undef COMPUTET
#undef COMPUTET_I
#undef BUF_A
#undef BUF_B
}

// ---------------- Kernel 5: flash attention, MFMA, fixed bound ----------------
// Block = 256 thr = 4 waves, wave w = head blockIdx.y*4+w; 32 q rows; S key-splits.
__global__ __launch_bounds__(256) void gat_attn_mfma(const short* __restrict__ bh,
                                                     const float* __restrict__ ss,
                                                     const float* __restrict__ st,
                                                     const float* __restrict__ stmax,
                                                     const float* __restrict__ mask,
                                                     const uint32_t* __restrict__ mflag,
                                                     float* __restrict__ acc_p,
                                                     float* __restrict__ l_p,
                                                     int S) {
    const int lane = threadIdx.x & 63;
    const int h = blockIdx.y * 4 + (threadIdx.x >> 6);
    const int q0 = blockIdx.x * 32;
    const int s = blockIdx.z;
    const int TPS = 128 / S;                 // 32-key tiles per split (S<=4 -> TPS even)
    const int g = lane >> 4;

    const int qa = q0 + (lane & 15);
    const int qb = qa + 16;
    const float ssa = ss[h * GN + qa];
    const float ssb = ss[h * GN + qb];
    const float smx = stmax[h];
    const float caL = leaky(ssa + smx) * LOG2E;   // fixed softmax bound (log2 domain)
    const float cbL = leaky(ssb + smx) * LOG2E;
    // exponent = max(stv*L + KP, 0.2*stv*L + KN) (+ mask*L)
    const float KaP = fmaf(ssa, LOG2E, -caL), KaN = fmaf(0.2f * ssa, LOG2E, -caL);
    const float KbP = fmaf(ssb, LOG2E, -cbL), KbN = fmaf(0.2f * ssb, LOG2E, -cbL);

    f32x4 acc[2][4];
#pragma unroll
    for (int qf = 0; qf < 2; ++qf)
#pragma unroll
        for (int cf = 0; cf < 4; ++cf) acc[qf][cf] = (f32x4){0.f, 0.f, 0.f, 0.f};
    f32x4 accLa = (f32x4){0.f, 0.f, 0.f, 0.f};
    f32x4 accLb = (f32x4){0.f, 0.f, 0.f, 0.f};

    const int t0 = s * TPS;
    const float4* stp = (const float4*)&st[h * GN + t0 * 32 + g * 8];
    const float4* mpa = (const float4*)&mask[(size_t)qa * GN + t0 * 32 + g * 8];
    const float4* mpb = (const float4*)&mask[(size_t)qb * GN + t0 * 32 + g * 8];
    const short8v* bhp = (const short8v*)bh + ((size_t)(h * 128 + t0) * 4) * 64 + lane;

    if (mflag[0] != 0u)
        attn_pipeline<true >(stp, mpa, mpb, bhp, TPS, KaP, KaN, KbP, KbN, acc, accLa, accLb);
    else
        attn_pipeline<false>(stp, mpa, mpb, bhp, TPS, KaP, KaN, KbP, KbN, acc, accLa, accLb);

    // row-sums from ones-MFMA: D[row = g*4+r, col] identical across cols; store once per row
    if ((lane & 15) == 0) {
#pragma unroll
        for (int r = 0; r < 4; ++r) {
            l_p[(size_t)(s * GH + h) * GN + q0 + g * 4 + r]      = accLa[r];
            l_p[(size_t)(s * GH + h) * GN + q0 + 16 + g * 4 + r] = accLb[r];
        }
    }
    // store partial acc: D layout col=lane&15, row=(lane>>4)*4+r
#pragma unroll
    for (int qf = 0; qf < 2; ++qf)
#pragma unroll
        for (int cf = 0; cf < 4; ++cf)
#pragma unroll
            for (int r = 0; r < 4; ++r) {
                int row = q0 + qf * 16 + (lane >> 4) * 4 + r;
                int col = cf * 16 + (lane & 15);
                acc_p[((size_t)(s * GH + h) * GN + row) * GF + col] = acc[qf][cf][r];
            }
}

// ---------------- Kernel 6: combine splits, head-mean, relu (float4) ----------------
__global__ __launch_bounds__(256) void gat_combine(const float* __restrict__ acc_p,
                                                   const float* __restrict__ l_p,
                                                   float* __restrict__ out, int S) {
    const int idx = blockIdx.x * 256 + threadIdx.x;    // n*16 + f4
    const int n = idx >> 4, f4 = idx & 15;
    const float4* ap = (const float4*)acc_p;
    float4 r = {0.f, 0.f, 0.f, 0.f};
#pragma unroll
    for (int h = 0; h < GH; ++h) {
        float4 a = {0.f, 0.f, 0.f, 0.f};
        float l = 0.f;
        for (int s = 0; s < S; ++s) {
            float4 v = ap[((size_t)(s * GH + h) * GN + n) * 16 + f4];
            a.x += v.x; a.y += v.y; a.z += v.z; a.w += v.w;
            l += l_p[(size_t)(s * GH + h) * GN + n];
        }
        float il = 1.0f / l;
        r.x += a.x * il; r.y += a.y * il; r.z += a.z * il; r.w += a.w * il;
    }
    float4 o;
    o.x = fmaxf(r.x * 0.125f, 0.f);
    o.y = fmaxf(r.y * 0.125f, 0.f);
    o.z = fmaxf(r.z * 0.125f, 0.f);
    o.w = fmaxf(r.w * 0.125f, 0.f);
    ((float4*)out)[idx] = o;
}

extern "C" void kernel_launch(void* const* d_in, const int* in_sizes, int n_in,
                              void* d_out, int out_size, void* d_ws, size_t ws_size,
                              hipStream_t stream) {
    const float* A     = (const float*)d_in[0];
    const float* mask  = (const float*)d_in[1];
    const float* Wp    = (const float*)d_in[2];
    const float* a_src = (const float*)d_in[3];
    const float* a_tgt = (const float*)d_in[4];
    float* out = (float*)d_out;

    char* w = (char*)d_ws;
    float* xp    = (float*)w;              w += (size_t)GN * GHF * 4;        // 8 MB
    float* ss    = (float*)w;              w += (size_t)GH * GN * 4;
    float* st    = (float*)w;              w += (size_t)GH * GN * 4;
    float* stmx  = (float*)w;              w += 256;
    uint32_t* mflag = (uint32_t*)w;        w += 256;
    short* bh    = (short*)w;              w += (size_t)GH * 128 * 4 * 64 * 8 * 2; // 4 MB
    size_t base = (size_t)(w - (char*)d_ws);
    size_t per_s = (size_t)GH * GN * GF * 4 + (size_t)GH * GN * 4;           // 8.5 MB
    int S = 4;
    while (S > 1 && base + (size_t)S * per_s > ws_size) S >>= 1;
    float* acc_p = (float*)w;              w += (size_t)S * GH * GN * GF * 4;
    float* l_p   = (float*)w;

    gat_zeroflag<<<1, 64, 0, stream>>>(mflag);
    gat_maskscan<<<2048, 256, 0, stream>>>((const uint32_t*)mask, mflag);
    gat_proj<<<dim3(GN / 64, GHF / 64), 256, 0, stream>>>(A, Wp, xp);
    gat_scores<<<(GH * GN) / 4, 256, 0, stream>>>(xp, a_src, a_tgt, ss, st);
    gat_stmax<<<GH, 256, 0, stream>>>(st, stmx);
    gat_fragconv<<<(GH * 128 * 4 * 64) / 256, 256, 0, stream>>>(xp, bh);
    gat_attn_mfma<<<dim3(GN / 32, 2, S), 256, 0, stream>>>(bh, ss, st, stmx, mask,
                                                           mflag, acc_p, l_p, S);
    gat_combine<<<(GN * 16) / 256, 256, 0, stream>>>(acc_p, l_p, out, S);
}

// Round 9
// 102.401 us; speedup vs baseline: 1.8027x; 1.0035x over previous
//
#include <hip/hip_runtime.h>
#include <hip/hip_bf16.h>
#include <cstdint>

#define GN 4096      // N nodes
#define GIN 128      // IN_F
#define GF 64        // OUT_F
#define GH 8         // heads
#define GHF (GH*GF)  // 512
#define LOG2E 1.4426950408889634f

typedef __attribute__((ext_vector_type(8))) short short8v;
typedef __attribute__((ext_vector_type(4))) float f32x4;

__device__ __forceinline__ short f2bf(float x) {           // RNE float->bf16
    uint32_t u = __float_as_uint(x);
    uint32_t r = u + 0x7fffu + ((u >> 16) & 1u);
    return (short)(r >> 16);
}
__device__ __forceinline__ float leaky(float t) { return fmaxf(t, 0.2f * t); }
__device__ __forceinline__ uint32_t cvt_pk_bf16(float lo, float hi) {
    uint32_t r;
    asm("v_cvt_pk_bf16_f32 %0, %1, %2" : "=v"(r) : "v"(lo), "v"(hi));
    return r;
}

// ---------------- Kernel 0a/0b: mask zero-detection (exact) ----------------
__global__ void gat_zeroflag(uint32_t* __restrict__ f) {
    if (threadIdx.x == 0 && blockIdx.x == 0) f[0] = 0u;
}
__global__ __launch_bounds__(256) void gat_maskscan(const uint32_t* __restrict__ m,
                                                    uint32_t* __restrict__ flag) {
    uint32_t acc = 0;
    const uint4* m4 = (const uint4*)m;
    const int total = (GN * GN) / 4;           // uint4 count
    for (int i = blockIdx.x * 256 + threadIdx.x; i < total; i += gridDim.x * 256) {
        uint4 v = m4[i];
        acc |= v.x | v.y | v.z | v.w;
    }
#pragma unroll
    for (int d = 1; d < 64; d <<= 1) acc |= (uint32_t)__shfl_xor((int)acc, d);
    __shared__ uint32_t wred[4];
    if ((threadIdx.x & 63) == 0) wred[threadIdx.x >> 6] = acc;
    __syncthreads();
    if (threadIdx.x == 0) {
        uint32_t a = wred[0] | wred[1] | wred[2] | wred[3];
        if (a) atomicOr(flag, 1u);
    }
}

// ---------------- Kernel 1: fused projection + scores + fragconv ----------------
// Block (n0=bx*64 rows, head=by). Computes the 64x64 fp32 tile, then from LDS:
// ss/st rows, and bh MFMA B-fragments. xp never hits HBM.
__global__ __launch_bounds__(256) void gat_proj(const float* __restrict__ A,
                                                const float* __restrict__ W,
                                                const float* __restrict__ a_src,
                                                const float* __restrict__ a_tgt,
                                                float* __restrict__ ss,
                                                float* __restrict__ st,
                                                short* __restrict__ bh) {
    __shared__ float lds[2 * 64 * 129];
    float* As = lds;               // [64][129]
    float* Ws = lds + 64 * 129;    // [64][129]
    const int n0 = blockIdx.x * 64;
    const int h  = blockIdx.y;
    const int j0 = h * 64;
    const int tid = threadIdx.x;
    const float4* A4 = (const float4*)A;
    const float4* W4 = (const float4*)W;
#pragma unroll
    for (int i = 0; i < 8; ++i) {
        int idx = tid + i * 256;
        int r = idx >> 5, c4 = idx & 31;
        float4 v = A4[(size_t)(n0 + r) * 32 + c4];
        As[r * 129 + c4 * 4 + 0] = v.x; As[r * 129 + c4 * 4 + 1] = v.y;
        As[r * 129 + c4 * 4 + 2] = v.z; As[r * 129 + c4 * 4 + 3] = v.w;
        float4 w = W4[(size_t)(j0 + r) * 32 + c4];
        Ws[r * 129 + c4 * 4 + 0] = w.x; Ws[r * 129 + c4 * 4 + 1] = w.y;
        Ws[r * 129 + c4 * 4 + 2] = w.z; Ws[r * 129 + c4 * 4 + 3] = w.w;
    }
    __syncthreads();
    const int tx = tid & 15, ty = tid >> 4;
    float acc[4][4] = {};
    for (int k = 0; k < 128; ++k) {
        float a[4], b[4];
#pragma unroll
        for (int i = 0; i < 4; ++i) { a[i] = As[(ty * 4 + i) * 129 + k]; b[i] = Ws[(tx * 4 + i) * 129 + k]; }
#pragma unroll
        for (int i = 0; i < 4; ++i)
#pragma unroll
            for (int j = 0; j < 4; ++j) acc[i][j] = fmaf(a[i], b[j], acc[i][j]);
    }
    __syncthreads();                       // done with As/Ws contents
    // stage X = [64][65] fp32 tile in the As region
    float* X = lds;
#pragma unroll
    for (int i = 0; i < 4; ++i)
#pragma unroll
        for (int j = 0; j < 4; ++j)
            X[(ty * 4 + i) * 65 + tx * 4 + j] = acc[i][j];
    __syncthreads();

    // scores: lane = local row, wave w covers f-chunk [w*16, w*16+16)
    const int lane = tid & 63, w = tid >> 6;
    float s1 = 0.f, s2 = 0.f;
#pragma unroll
    for (int k = 0; k < 16; ++k) {
        int f = w * 16 + k;
        float x = X[lane * 65 + f];
        s1 = fmaf(x, a_src[j0 + f], s1);
        s2 = fmaf(x, a_tgt[j0 + f], s2);
    }
    float* ps = lds + 64 * 129;            // reuse Ws region: [8][64]
    ps[w * 64 + lane] = s1;
    ps[(4 + w) * 64 + lane] = s2;
    __syncthreads();
    if (w == 0) {
        ss[h * GN + n0 + lane] = ps[lane] + ps[64 + lane] + ps[128 + lane] + ps[192 + lane];
        st[h * GN + n0 + lane] = ps[256 + lane] + ps[320 + lane] + ps[384 + lane] + ps[448 + lane];
    }

    // fragconv: 512 frags per block (2 t_local x 4 cf x 64 lanes) -> 2 per thread
#pragma unroll
    for (int rep = 0; rep < 2; ++rep) {
        int fid = tid + rep * 256;
        int t_local = fid >> 8, cf = (fid >> 6) & 3, lf = fid & 63;
        int gg = lf >> 4, c = lf & 15;
        short8v vh;
#pragma unroll
        for (int jj = 0; jj < 8; ++jj)
            vh[jj] = f2bf(X[(t_local * 32 + gg * 8 + jj) * 65 + cf * 16 + c]);
        ((short8v*)bh)[((size_t)(h * 128 + (n0 >> 5) + t_local) * 4 + cf) * 64 + lf] = vh;
    }
}

// ---------------- Kernel 3: stmax[h] = max_n st[h][n] (one block per head) ----------------
__global__ __launch_bounds__(256) void gat_stmax(const float* __restrict__ st,
                                                 float* __restrict__ stmax) {
    const int h = blockIdx.x;
    const int tid = threadIdx.x;
    float m = -1e30f;
    for (int i = tid; i < GN; i += 256) m = fmaxf(m, st[h * GN + i]);
#pragma unroll
    for (int d = 1; d < 64; d <<= 1) m = fmaxf(m, __shfl_xor(m, d));
    __shared__ float wred[4];
    if ((tid & 63) == 0) wred[tid >> 6] = m;
    __syncthreads();
    if (tid == 0)
        stmax[h] = fmaxf(fmaxf(wred[0], wred[1]), fmaxf(wred[2], wred[3]));
}

// ---------------- attn pipeline (depth-1 reg prefetch), 16 q-rows/wave ----------------
template<bool HM>
__device__ __forceinline__ void attn_pipeline(const float4* stp, const float4* mpa,
                                              const short8v* bhp, int TPS,
                                              float KaP, float KaN,
                                              f32x4 (&acc)[4], f32x4& accL) {
    const short BONE = (short)0x3F80;            // bf16 1.0
    const short8v BONES = {BONE, BONE, BONE, BONE, BONE, BONE, BONE, BONE};

    float4 sA0, sA1, aA0, aA1; short8v BhA0, BhA1, BhA2, BhA3;
    float4 sB0, sB1, aB0, aB1; short8v BhB0, BhB1, BhB2, BhB3;

// NOTE: one level of macro indirection so BUF_A/BUF_B expand BEFORE arg matching.
#define LOADT_I(s0,s1,a0,a1,H0,H1,H2,H3) do { \
    s0 = stp[0]; s1 = stp[1]; stp += 8;       \
    if constexpr (HM) { a0 = mpa[0]; a1 = mpa[1]; mpa += 8; } \
    H0 = bhp[0]; H1 = bhp[64]; H2 = bhp[128]; H3 = bhp[192]; bhp += 256; } while (0)
#define LOADT(...) LOADT_I(__VA_ARGS__)

#define COMPUTET_I(s0,s1,a0,a1,H0,H1,H2,H3) do {                            \
    float stv[8] = {s0.x, s0.y, s0.z, s0.w, s1.x, s1.y, s1.z, s1.w};        \
    float mav[8];                                                           \
    if constexpr (HM) {                                                     \
        mav[0]=a0.x; mav[1]=a0.y; mav[2]=a0.z; mav[3]=a0.w;                 \
        mav[4]=a1.x; mav[5]=a1.y; mav[6]=a1.z; mav[7]=a1.w;                 \
    }                                                                       \
    float pa[8];                                                            \
    _Pragma("unroll")                                                       \
    for (int j = 0; j < 8; ++j) {                                           \
        float stvL = stv[j] * LOG2E;                                        \
        float ea = fmaxf(stvL + KaP, fmaf(stvL, 0.2f, KaN));                \
        if constexpr (HM) ea = fmaf(mav[j], LOG2E, ea);                     \
        pa[j] = __builtin_amdgcn_exp2f(ea);                                 \
    }                                                                       \
    union { uint32_t u[4]; short8v v; } Pa;                                 \
    _Pragma("unroll")                                                       \
    for (int w = 0; w < 4; ++w)                                             \
        Pa.u[w] = cvt_pk_bf16(pa[2 * w], pa[2 * w + 1]);                    \
    acc[0] = __builtin_amdgcn_mfma_f32_16x16x32_bf16(Pa.v, H0, acc[0], 0, 0, 0); \
    acc[1] = __builtin_amdgcn_mfma_f32_16x16x32_bf16(Pa.v, H1, acc[1], 0, 0, 0); \
    acc[2] = __builtin_amdgcn_mfma_f32_16x16x32_bf16(Pa.v, H2, acc[2], 0, 0, 0); \
    acc[3] = __builtin_amdgcn_mfma_f32_16x16x32_bf16(Pa.v, H3, acc[3], 0, 0, 0); \
    accL   = __builtin_amdgcn_mfma_f32_16x16x32_bf16(Pa.v, BONES, accL, 0, 0, 0); \
    } while (0)
#define COMPUTET(...) COMPUTET_I(__VA_ARGS__)

#define BUF_A sA0, sA1, aA0, aA1, BhA0, BhA1, BhA2, BhA3
#define BUF_B sB0, sB1, aB0, aB1, BhB0, BhB1, BhB2, BhB3

    LOADT(BUF_A);                       // tile t0
    for (int t = 0; t + 2 < TPS; t += 2) {
        LOADT(BUF_B);                   // tile t+1 in flight during compute of t
        COMPUTET(BUF_A);
        LOADT(BUF_A);                   // tile t+2 in flight during compute of t+1
        COMPUTET(BUF_B);
    }
    LOADT(BUF_B);                       // last tile (no further prefetch)
    COMPUTET(BUF_A);
    COMPUTET(BUF_B);

#undef LOADT
#undef LOADT_I
#undef COMPUTET
#undef COMPUTET_I
#undef BUF_A
#undef BUF_B
}

// ---------------- Kernel 5: flash attention, MFMA, fixed bound, q16-split ----------------
// Block = 256 thr = 4 waves, wave w = head by*4+w; 16 q rows per wave; S key-splits.
__global__ __launch_bounds__(256) void gat_attn_mfma(const short* __restrict__ bh,
                                                     const float* __restrict__ ss,
                                                     const float* __restrict__ st,
                                                     const float* __restrict__ stmax,
                                                     const float* __restrict__ mask,
                                                     const uint32_t* __restrict__ mflag,
                                                     float* __restrict__ acc_p,
                                                     float* __restrict__ l_p,
                                                     int S) {
    const int lane = threadIdx.x & 63;
    const int h = blockIdx.y * 4 + (threadIdx.x >> 6);
    const int q0 = blockIdx.x * 16;
    const int s = blockIdx.z;
    const int TPS = 128 / S;                 // 32-key tiles per split (S<=4 -> TPS even)
    const int g = lane >> 4;

    const int qa = q0 + (lane & 15);
    const float ssa = ss[h * GN + qa];
    const float smx = stmax[h];
    const float caL = leaky(ssa + smx) * LOG2E;   // fixed softmax bound (log2 domain)
    // exponent = max(stv*L + KaP, 0.2*stv*L + KaN) (+ mask*L)
    const float KaP = fmaf(ssa, LOG2E, -caL), KaN = fmaf(0.2f * ssa, LOG2E, -caL);

    f32x4 acc[4];
#pragma unroll
    for (int cf = 0; cf < 4; ++cf) acc[cf] = (f32x4){0.f, 0.f, 0.f, 0.f};
    f32x4 accL = (f32x4){0.f, 0.f, 0.f, 0.f};

    const int t0 = s * TPS;
    const float4* stp = (const float4*)&st[h * GN + t0 * 32 + g * 8];
    const float4* mpa = (const float4*)&mask[(size_t)qa * GN + t0 * 32 + g * 8];
    const short8v* bhp = (const short8v*)bh + ((size_t)(h * 128 + t0) * 4) * 64 + lane;

    if (mflag[0] != 0u)
        attn_pipeline<true >(stp, mpa, bhp, TPS, KaP, KaN, acc, accL);
    else
        attn_pipeline<false>(stp, mpa, bhp, TPS, KaP, KaN, acc, accL);

    // row-sums from ones-MFMA: D[row = g*4+r] identical across cols; store once per row
    if ((lane & 15) == 0) {
#pragma unroll
        for (int r = 0; r < 4; ++r)
            l_p[(size_t)(s * GH + h) * GN + q0 + g * 4 + r] = accL[r];
    }
    // store acc: D layout col=lane&15, row=g*4+r
#pragma unroll
    for (int cf = 0; cf < 4; ++cf)
#pragma unroll
        for (int r = 0; r < 4; ++r)
            acc_p[((size_t)(s * GH + h) * GN + q0 + g * 4 + r) * GF + cf * 16 + (lane & 15)]
                = acc[cf][r];
}

// ---------------- Kernel 6: combine splits, head-mean, relu (float4) ----------------
__global__ __launch_bounds__(256) void gat_combine(const float* __restrict__ acc_p,
                                                   const float* __restrict__ l_p,
                                                   float* __restrict__ out, int S) {
    const int idx = blockIdx.x * 256 + threadIdx.x;    // n*16 + f4
    const int n = idx >> 4, f4 = idx & 15;
    const float4* ap = (const float4*)acc_p;
    float4 r = {0.f, 0.f, 0.f, 0.f};
#pragma unroll
    for (int h = 0; h < GH; ++h) {
        float4 a = {0.f, 0.f, 0.f, 0.f};
        float l = 0.f;
        for (int s = 0; s < S; ++s) {
            float4 v = ap[((size_t)(s * GH + h) * GN + n) * 16 + f4];
            a.x += v.x; a.y += v.y; a.z += v.z; a.w += v.w;
            l += l_p[(size_t)(s * GH + h) * GN + n];
        }
        float il = 1.0f / l;
        r.x += a.x * il; r.y += a.y * il; r.z += a.z * il; r.w += a.w * il;
    }
    float4 o;
    o.x = fmaxf(r.x * 0.125f, 0.f);
    o.y = fmaxf(r.y * 0.125f, 0.f);
    o.z = fmaxf(r.z * 0.125f, 0.f);
    o.w = fmaxf(r.w * 0.125f, 0.f);
    ((float4*)out)[idx] = o;
}

extern "C" void kernel_launch(void* const* d_in, const int* in_sizes, int n_in,
                              void* d_out, int out_size, void* d_ws, size_t ws_size,
                              hipStream_t stream) {
    const float* A     = (const float*)d_in[0];
    const float* mask  = (const float*)d_in[1];
    const float* Wp    = (const float*)d_in[2];
    const float* a_src = (const float*)d_in[3];
    const float* a_tgt = (const float*)d_in[4];
    float* out = (float*)d_out;

    char* w = (char*)d_ws;
    float* ss    = (float*)w;              w += (size_t)GH * GN * 4;
    float* st    = (float*)w;              w += (size_t)GH * GN * 4;
    float* stmx  = (float*)w;              w += 256;
    uint32_t* mflag = (uint32_t*)w;        w += 256;
    short* bh    = (short*)w;              w += (size_t)GH * 128 * 4 * 64 * 8 * 2; // 4 MB
    size_t base = (size_t)(w - (char*)d_ws);
    size_t per_s = (size_t)GH * GN * GF * 4 + (size_t)GH * GN * 4;           // 8.5 MB
    int S = 4;
    while (S > 1 && base + (size_t)S * per_s > ws_size) S >>= 1;
    float* acc_p = (float*)w;              w += (size_t)S * GH * GN * GF * 4;
    float* l_p   = (float*)w;

    gat_zeroflag<<<1, 64, 0, stream>>>(mflag);
    gat_maskscan<<<2048, 256, 0, stream>>>((const uint32_t*)mask, mflag);
    gat_proj<<<dim3(GN / 64, GH), 256, 0, stream>>>(A, Wp, a_src, a_tgt, ss, st, bh);
    gat_stmax<<<GH, 256, 0, stream>>>(st, stmx);
    gat_attn_mfma<<<dim3(GN / 16, 2, S), 256, 0, stream>>>(bh, ss, st, stmx, mask,
                                                           mflag, acc_p, l_p, S);
    gat_combine<<<(GN * 16) / 256, 256, 0, stream>>>(acc_p, l_p, out, S);
}

// Round 10
// 87.765 us; speedup vs baseline: 2.1033x; 1.1668x over previous
//
#include <hip/hip_runtime.h>
#include <hip/hip_bf16.h>
#include <cstdint>

#define GN 4096      // N nodes
#define GIN 128      // IN_F
#define GF 64        // OUT_F
#define GH 8         // heads
#define GHF (GH*GF)  // 512
#define LOG2E 1.4426950408889634f

typedef __attribute__((ext_vector_type(8))) short short8v;
typedef __attribute__((ext_vector_type(4))) float f32x4;

__device__ __forceinline__ short f2bf(float x) {           // RNE float->bf16
    uint32_t u = __float_as_uint(x);
    uint32_t r = u + 0x7fffu + ((u >> 16) & 1u);
    return (short)(r >> 16);
}
__device__ __forceinline__ float leaky(float t) { return fmaxf(t, 0.2f * t); }
__device__ __forceinline__ uint32_t cvt_pk_bf16(float lo, float hi) {
    uint32_t r;
    asm("v_cvt_pk_bf16_f32 %0, %1, %2" : "=v"(r) : "v"(lo), "v"(hi));
    return r;
}

// ---------------- Kernel 0a/0b: mask zero-detection (exact) ----------------
__global__ void gat_zeroflag(uint32_t* __restrict__ f) {
    if (threadIdx.x == 0 && blockIdx.x == 0) f[0] = 0u;
}
__global__ __launch_bounds__(256) void gat_maskscan(const uint32_t* __restrict__ m,
                                                    uint32_t* __restrict__ flag) {
    uint32_t acc = 0;
    const uint4* m4 = (const uint4*)m;
    const int total = (GN * GN) / 4;           // uint4 count
    for (int i = blockIdx.x * 256 + threadIdx.x; i < total; i += gridDim.x * 256) {
        uint4 v = m4[i];
        acc |= v.x | v.y | v.z | v.w;
    }
#pragma unroll
    for (int d = 1; d < 64; d <<= 1) acc |= (uint32_t)__shfl_xor((int)acc, d);
    __shared__ uint32_t wred[4];
    if ((threadIdx.x & 63) == 0) wred[threadIdx.x >> 6] = acc;
    __syncthreads();
    if (threadIdx.x == 0) {
        uint32_t a = wred[0] | wred[1] | wred[2] | wred[3];
        if (a) atomicOr(flag, 1u);
    }
}

// ---------------- Kernel 1: fused projection + scores + fragconv ----------------
__global__ __launch_bounds__(256) void gat_proj(const float* __restrict__ A,
                                                const float* __restrict__ W,
                                                const float* __restrict__ a_src,
                                                const float* __restrict__ a_tgt,
                                                float* __restrict__ ss,
                                                float* __restrict__ st,
                                                short* __restrict__ bh) {
    __shared__ float lds[2 * 64 * 129];
    float* As = lds;               // [64][129]
    float* Ws = lds + 64 * 129;    // [64][129]
    const int n0 = blockIdx.x * 64;
    const int h  = blockIdx.y;
    const int j0 = h * 64;
    const int tid = threadIdx.x;
    const float4* A4 = (const float4*)A;
    const float4* W4 = (const float4*)W;
#pragma unroll
    for (int i = 0; i < 8; ++i) {
        int idx = tid + i * 256;
        int r = idx >> 5, c4 = idx & 31;
        float4 v = A4[(size_t)(n0 + r) * 32 + c4];
        As[r * 129 + c4 * 4 + 0] = v.x; As[r * 129 + c4 * 4 + 1] = v.y;
        As[r * 129 + c4 * 4 + 2] = v.z; As[r * 129 + c4 * 4 + 3] = v.w;
        float4 w = W4[(size_t)(j0 + r) * 32 + c4];
        Ws[r * 129 + c4 * 4 + 0] = w.x; Ws[r * 129 + c4 * 4 + 1] = w.y;
        Ws[r * 129 + c4 * 4 + 2] = w.z; Ws[r * 129 + c4 * 4 + 3] = w.w;
    }
    __syncthreads();
    const int tx = tid & 15, ty = tid >> 4;
    float acc[4][4] = {};
    for (int k = 0; k < 128; ++k) {
        float a[4], b[4];
#pragma unroll
        for (int i = 0; i < 4; ++i) { a[i] = As[(ty * 4 + i) * 129 + k]; b[i] = Ws[(tx * 4 + i) * 129 + k]; }
#pragma unroll
        for (int i = 0; i < 4; ++i)
#pragma unroll
            for (int j = 0; j < 4; ++j) acc[i][j] = fmaf(a[i], b[j], acc[i][j]);
    }
    __syncthreads();                       // done with As/Ws contents
    float* X = lds;                        // stage X = [64][65] fp32 tile
#pragma unroll
    for (int i = 0; i < 4; ++i)
#pragma unroll
        for (int j = 0; j < 4; ++j)
            X[(ty * 4 + i) * 65 + tx * 4 + j] = acc[i][j];
    __syncthreads();

    const int lane = tid & 63, w = tid >> 6;
    float s1 = 0.f, s2 = 0.f;
#pragma unroll
    for (int k = 0; k < 16; ++k) {
        int f = w * 16 + k;
        float x = X[lane * 65 + f];
        s1 = fmaf(x, a_src[j0 + f], s1);
        s2 = fmaf(x, a_tgt[j0 + f], s2);
    }
    float* ps = lds + 64 * 129;            // reuse Ws region: [8][64]
    ps[w * 64 + lane] = s1;
    ps[(4 + w) * 64 + lane] = s2;
    __syncthreads();
    if (w == 0) {
        ss[h * GN + n0 + lane] = ps[lane] + ps[64 + lane] + ps[128 + lane] + ps[192 + lane];
        st[h * GN + n0 + lane] = ps[256 + lane] + ps[320 + lane] + ps[384 + lane] + ps[448 + lane];
    }

#pragma unroll
    for (int rep = 0; rep < 2; ++rep) {
        int fid = tid + rep * 256;
        int t_local = fid >> 8, cf = (fid >> 6) & 3, lf = fid & 63;
        int gg = lf >> 4, c = lf & 15;
        short8v vh;
#pragma unroll
        for (int jj = 0; jj < 8; ++jj)
            vh[jj] = f2bf(X[(t_local * 32 + gg * 8 + jj) * 65 + cf * 16 + c]);
        ((short8v*)bh)[((size_t)(h * 128 + (n0 >> 5) + t_local) * 4 + cf) * 64 + lf] = vh;
    }
}

// ---------------- Kernel 3: stmax[h] = max_n st[h][n] (one block per head) ----------------
__global__ __launch_bounds__(256) void gat_stmax(const float* __restrict__ st,
                                                 float* __restrict__ stmax) {
    const int h = blockIdx.x;
    const int tid = threadIdx.x;
    float m = -1e30f;
    for (int i = tid; i < GN; i += 256) m = fmaxf(m, st[h * GN + i]);
#pragma unroll
    for (int d = 1; d < 64; d <<= 1) m = fmaxf(m, __shfl_xor(m, d));
    __shared__ float wred[4];
    if ((tid & 63) == 0) wred[tid >> 6] = m;
    __syncthreads();
    if (tid == 0)
        stmax[h] = fmaxf(fmaxf(wred[0], wred[1]), fmaxf(wred[2], wred[3]));
}

// ---------------- Kernel 5a: FAST attention (mask known zero), q64 per wave ----------------
// Block = 256 thr = 4 waves, wave w = head by*4+w; 64 q rows per wave; S key-splits.
__global__ __launch_bounds__(256) void gat_attn_fast(const short* __restrict__ bh,
                                                     const float* __restrict__ ss,
                                                     const float* __restrict__ st,
                                                     const float* __restrict__ stmax,
                                                     const uint32_t* __restrict__ mflag,
                                                     float* __restrict__ acc_p,
                                                     float* __restrict__ l_p,
                                                     int S) {
    if (mflag[0] != 0u) return;              // mask nonzero -> handled by gat_attn_mask
    const int lane = threadIdx.x & 63;
    const int h = blockIdx.y * 4 + (threadIdx.x >> 6);
    const int q0 = blockIdx.x * 64;
    const int s = blockIdx.z;
    const int TPS = 128 / S;
    const int g = lane >> 4;
    const int c = lane & 15;

    const float smx = stmax[h];
    float KP[4], KN[4];
#pragma unroll
    for (int qf = 0; qf < 4; ++qf) {
        float ssa = ss[h * GN + q0 + qf * 16 + c];
        float caL = leaky(ssa + smx) * LOG2E;      // fixed softmax bound (log2 domain)
        KP[qf] = fmaf(ssa, LOG2E, -caL);
        KN[qf] = fmaf(0.2f * ssa, LOG2E, -caL);
    }

    const short BONE = (short)0x3F80;              // bf16 1.0
    const short8v BONES = {BONE, BONE, BONE, BONE, BONE, BONE, BONE, BONE};

    f32x4 acc[4][4];
    f32x4 accL[4];
#pragma unroll
    for (int qf = 0; qf < 4; ++qf) {
        accL[qf] = (f32x4){0.f, 0.f, 0.f, 0.f};
#pragma unroll
        for (int cf = 0; cf < 4; ++cf) acc[qf][cf] = (f32x4){0.f, 0.f, 0.f, 0.f};
    }

    const int t0 = s * TPS;
    const float4* stp = (const float4*)&st[h * GN + t0 * 32 + g * 8];
    const short8v* bhp = (const short8v*)bh + ((size_t)(h * 128 + t0) * 4) * 64 + lane;

    float4 sA[2]; short8v HA[4];
    float4 sB[2]; short8v HB[4];

#define LOADT(sv, Hv) do {                                      \
    sv[0] = stp[0]; sv[1] = stp[1]; stp += 8;                   \
    _Pragma("unroll")                                           \
    for (int i = 0; i < 4; ++i) Hv[i] = bhp[i * 64];            \
    bhp += 256; } while (0)

#define COMPUTET(sv, Hv) do {                                               \
    float stvL[8] = {sv[0].x * LOG2E, sv[0].y * LOG2E, sv[0].z * LOG2E,     \
                     sv[0].w * LOG2E, sv[1].x * LOG2E, sv[1].y * LOG2E,     \
                     sv[1].z * LOG2E, sv[1].w * LOG2E};                     \
    _Pragma("unroll")                                                       \
    for (int qf = 0; qf < 4; ++qf) {                                        \
        float pa[8];                                                        \
        _Pragma("unroll")                                                   \
        for (int j = 0; j < 8; ++j) {                                       \
            float ea = fmaxf(stvL[j] + KP[qf], fmaf(stvL[j], 0.2f, KN[qf])); \
            pa[j] = __builtin_amdgcn_exp2f(ea);                             \
        }                                                                   \
        union { uint32_t u[4]; short8v v; } P;                              \
        _Pragma("unroll")                                                   \
        for (int w2 = 0; w2 < 4; ++w2)                                      \
            P.u[w2] = cvt_pk_bf16(pa[2 * w2], pa[2 * w2 + 1]);              \
        _Pragma("unroll")                                                   \
        for (int cf = 0; cf < 4; ++cf)                                      \
            acc[qf][cf] = __builtin_amdgcn_mfma_f32_16x16x32_bf16(P.v, Hv[cf], acc[qf][cf], 0, 0, 0); \
        accL[qf] = __builtin_amdgcn_mfma_f32_16x16x32_bf16(P.v, BONES, accL[qf], 0, 0, 0); \
    } } while (0)

    LOADT(sA, HA);                       // tile t0
    for (int t = 0; t + 2 < TPS; t += 2) {
        LOADT(sB, HB);                   // tile t+1 in flight during compute of t
        COMPUTET(sA, HA);
        LOADT(sA, HA);                   // tile t+2 in flight during compute of t+1
        COMPUTET(sB, HB);
    }
    LOADT(sB, HB);                       // last tile (no further prefetch)
    COMPUTET(sA, HA);
    COMPUTET(sB, HB);

#undef LOADT
#undef COMPUTET

    // row-sums from ones-MFMA: D[row = g*4+r] identical across cols; store once per row
    if (c == 0) {
#pragma unroll
        for (int qf = 0; qf < 4; ++qf)
#pragma unroll
            for (int r = 0; r < 4; ++r)
                l_p[(size_t)(s * GH + h) * GN + q0 + qf * 16 + g * 4 + r] = accL[qf][r];
    }
    // store acc: D layout col=c, row=g*4+r
#pragma unroll
    for (int qf = 0; qf < 4; ++qf)
#pragma unroll
        for (int cf = 0; cf < 4; ++cf)
#pragma unroll
            for (int r = 0; r < 4; ++r)
                acc_p[((size_t)(s * GH + h) * GN + q0 + qf * 16 + g * 4 + r) * GF + cf * 16 + c]
                    = acc[qf][cf][r];
}

// ---------------- Kernel 5b: MASK fallback attention (q16, r9-proven), guarded ----------------
__global__ __launch_bounds__(256) void gat_attn_mask(const short* __restrict__ bh,
                                                     const float* __restrict__ ss,
                                                     const float* __restrict__ st,
                                                     const float* __restrict__ stmax,
                                                     const float* __restrict__ mask,
                                                     const uint32_t* __restrict__ mflag,
                                                     float* __restrict__ acc_p,
                                                     float* __restrict__ l_p,
                                                     int S) {
    if (mflag[0] == 0u) return;              // mask zero -> handled by gat_attn_fast
    const int lane = threadIdx.x & 63;
    const int h = blockIdx.y * 4 + (threadIdx.x >> 6);
    const int q0 = blockIdx.x * 16;
    const int s = blockIdx.z;
    const int TPS = 128 / S;
    const int g = lane >> 4;

    const int qa = q0 + (lane & 15);
    const float ssa = ss[h * GN + qa];
    const float smx = stmax[h];
    const float caL = leaky(ssa + smx) * LOG2E;
    const float KaP = fmaf(ssa, LOG2E, -caL), KaN = fmaf(0.2f * ssa, LOG2E, -caL);

    const short BONE = (short)0x3F80;
    const short8v BONES = {BONE, BONE, BONE, BONE, BONE, BONE, BONE, BONE};

    f32x4 acc[4];
#pragma unroll
    for (int cf = 0; cf < 4; ++cf) acc[cf] = (f32x4){0.f, 0.f, 0.f, 0.f};
    f32x4 accL = (f32x4){0.f, 0.f, 0.f, 0.f};

    const int t0 = s * TPS;
    const float4* stp = (const float4*)&st[h * GN + t0 * 32 + g * 8];
    const float4* mpa = (const float4*)&mask[(size_t)qa * GN + t0 * 32 + g * 8];
    const short8v* bhp = (const short8v*)bh + ((size_t)(h * 128 + t0) * 4) * 64 + lane;

    for (int t = 0; t < TPS; ++t) {
        float4 s0 = stp[0], s1 = stp[1]; stp += 8;
        float4 a0 = mpa[0], a1 = mpa[1]; mpa += 8;
        short8v H[4];
#pragma unroll
        for (int i = 0; i < 4; ++i) H[i] = bhp[i * 64];
        bhp += 256;
        float stv[8] = {s0.x, s0.y, s0.z, s0.w, s1.x, s1.y, s1.z, s1.w};
        float mav[8] = {a0.x, a0.y, a0.z, a0.w, a1.x, a1.y, a1.z, a1.w};
        float pa[8];
#pragma unroll
        for (int j = 0; j < 8; ++j) {
            float stvL = stv[j] * LOG2E;
            float ea = fmaxf(stvL + KaP, fmaf(stvL, 0.2f, KaN));
            ea = fmaf(mav[j], LOG2E, ea);
            pa[j] = __builtin_amdgcn_exp2f(ea);
        }
        union { uint32_t u[4]; short8v v; } P;
#pragma unroll
        for (int w2 = 0; w2 < 4; ++w2) P.u[w2] = cvt_pk_bf16(pa[2 * w2], pa[2 * w2 + 1]);
#pragma unroll
        for (int cf = 0; cf < 4; ++cf)
            acc[cf] = __builtin_amdgcn_mfma_f32_16x16x32_bf16(P.v, H[cf], acc[cf], 0, 0, 0);
        accL = __builtin_amdgcn_mfma_f32_16x16x32_bf16(P.v, BONES, accL, 0, 0, 0);
    }

    if ((lane & 15) == 0) {
#pragma unroll
        for (int r = 0; r < 4; ++r)
            l_p[(size_t)(s * GH + h) * GN + q0 + g * 4 + r] = accL[r];
    }
#pragma unroll
    for (int cf = 0; cf < 4; ++cf)
#pragma unroll
        for (int r = 0; r < 4; ++r)
            acc_p[((size_t)(s * GH + h) * GN + q0 + g * 4 + r) * GF + cf * 16 + (lane & 15)]
                = acc[cf][r];
}

// ---------------- Kernel 6: combine splits, head-mean, relu (float4) ----------------
__global__ __launch_bounds__(256) void gat_combine(const float* __restrict__ acc_p,
                                                   const float* __restrict__ l_p,
                                                   float* __restrict__ out, int S) {
    const int idx = blockIdx.x * 256 + threadIdx.x;    // n*16 + f4
    const int n = idx >> 4, f4 = idx & 15;
    const float4* ap = (const float4*)acc_p;
    float4 r = {0.f, 0.f, 0.f, 0.f};
#pragma unroll
    for (int h = 0; h < GH; ++h) {
        float4 a = {0.f, 0.f, 0.f, 0.f};
        float l = 0.f;
        for (int s = 0; s < S; ++s) {
            float4 v = ap[((size_t)(s * GH + h) * GN + n) * 16 + f4];
            a.x += v.x; a.y += v.y; a.z += v.z; a.w += v.w;
            l += l_p[(size_t)(s * GH + h) * GN + n];
        }
        float il = 1.0f / l;
        r.x += a.x * il; r.y += a.y * il; r.z += a.z * il; r.w += a.w * il;
    }
    float4 o;
    o.x = fmaxf(r.x * 0.125f, 0.f);
    o.y = fmaxf(r.y * 0.125f, 0.f);
    o.z = fmaxf(r.z * 0.125f, 0.f);
    o.w = fmaxf(r.w * 0.125f, 0.f);
    ((float4*)out)[idx] = o;
}

extern "C" void kernel_launch(void* const* d_in, const int* in_sizes, int n_in,
                              void* d_out, int out_size, void* d_ws, size_t ws_size,
                              hipStream_t stream) {
    const float* A     = (const float*)d_in[0];
    const float* mask  = (const float*)d_in[1];
    const float* Wp    = (const float*)d_in[2];
    const float* a_src = (const float*)d_in[3];
    const float* a_tgt = (const float*)d_in[4];
    float* out = (float*)d_out;

    char* w = (char*)d_ws;
    float* ss    = (float*)w;              w += (size_t)GH * GN * 4;
    float* st    = (float*)w;              w += (size_t)GH * GN * 4;
    float* stmx  = (float*)w;              w += 256;
    uint32_t* mflag = (uint32_t*)w;        w += 256;
    short* bh    = (short*)w;              w += (size_t)GH * 128 * 4 * 64 * 8 * 2; // 4 MB
    size_t base = (size_t)(w - (char*)d_ws);
    size_t per_s = (size_t)GH * GN * GF * 4 + (size_t)GH * GN * 4;           // 8.5 MB
    int S = 4;
    while (S > 1 && base + (size_t)S * per_s > ws_size) S >>= 1;
    float* acc_p = (float*)w;              w += (size_t)S * GH * GN * GF * 4;
    float* l_p   = (float*)w;

    gat_zeroflag<<<1, 64, 0, stream>>>(mflag);
    gat_maskscan<<<2048, 256, 0, stream>>>((const uint32_t*)mask, mflag);
    gat_proj<<<dim3(GN / 64, GH), 256, 0, stream>>>(A, Wp, a_src, a_tgt, ss, st, bh);
    gat_stmax<<<GH, 256, 0, stream>>>(st, stmx);
    gat_attn_fast<<<dim3(GN / 64, 2, S), 256, 0, stream>>>(bh, ss, st, stmx,
                                                           mflag, acc_p, l_p, S);
    gat_attn_mask<<<dim3(GN / 16, 2, S), 256, 0, stream>>>(bh, ss, st, stmx, mask,
                                                           mflag, acc_p, l_p, S);
    gat_combine<<<(GN * 16) / 256, 256, 0, stream>>>(acc_p, l_p, out, S);
}